// Round 4
// baseline (548.960 us; speedup 1.0000x reference)
//
#include <hip/hip_runtime.h>
#include <cstdint>
#include <cmath>

// ---------------- problem constants ----------------
#define BS    2
#define CC    64
#define FLAT  16384
#define NN    2048
#define KK    256
#define EPSBN 1e-5f
#define TINYF 1.17549435e-38f
#define PE_SCALE -0.14391156831212787f
#define JAX_PARTITIONABLE 1

// ---------------- workspace layout (float offsets) ----------------
#define OFF_XI    0                          // [BS][NN][CC]
#define OFF_XI1   (OFF_XI   + BS*NN*CC)      // [BS][NN][32]
#define OFF_PROB  (OFF_XI1  + BS*NN*32)      // [BS][NN]
#define OFF_LOGP  (OFF_PROB + BS*NN)         // [BS][NN]
#define OFF_NEK   (OFF_LOGP + BS*NN)         // [BS][KK]
#define OFF_TF    (OFF_NEK  + BS*KK)         // [BS][KK][CC]
#define OFF_M1    (OFF_TF   + BS*KK*CC)      // [BS][KK][32]
#define OFF_DELTA (OFF_M1   + BS*KK*32)      // [BS][NN][CC]
#define OFF_WF    (OFF_DELTA+ BS*NN*CC)      // [256][64]
#define OFF_BF    (OFF_WF   + 256*CC)        // [64]
#define OFF_INV   (OFF_BF   + CC)            // [BS][FLAT] ints

// ---------------- threefry2x32 ----------------
__device__ __forceinline__ uint32_t rotl32(uint32_t x, int r) {
  return (x << r) | (x >> (32 - r));
}
__device__ __forceinline__ void tf2x32(uint32_t k0, uint32_t k1,
                                       uint32_t& x0, uint32_t& x1) {
  uint32_t k2 = k0 ^ k1 ^ 0x1BD11BDAu;
  x0 += k0; x1 += k1;
#define TFR(r) { x0 += x1; x1 = rotl32(x1, r); x1 ^= x0; }
  TFR(13) TFR(15) TFR(26) TFR(6)  x0 += k1; x1 += k2 + 1u;
  TFR(17) TFR(29) TFR(16) TFR(24) x0 += k2; x1 += k0 + 2u;
  TFR(13) TFR(15) TFR(26) TFR(6)  x0 += k0; x1 += k1 + 3u;
  TFR(17) TFR(29) TFR(16) TFR(24) x0 += k1; x1 += k2 + 4u;
  TFR(13) TFR(15) TFR(26) TFR(6)  x0 += k2; x1 += k0 + 5u;
#undef TFR
}
__device__ __forceinline__ void jax_key(int b, uint32_t& k0, uint32_t& k1) {
#if JAX_PARTITIONABLE
  uint32_t x0 = 0u, x1 = (uint32_t)b;
  tf2x32(0u, 42u, x0, x1);
  k0 = x0; k1 = x1;
#else
  uint32_t a0 = 0u, a1 = 2u, c0 = 1u, c1 = 3u;
  tf2x32(0u, 42u, a0, a1);
  tf2x32(0u, 42u, c0, c1);
  if (b == 0) { k0 = a0; k1 = c0; } else { k0 = a1; k1 = c1; }
#endif
}
__device__ __forceinline__ uint32_t jax_bits(uint32_t k0, uint32_t k1, uint32_t i) {
#if JAX_PARTITIONABLE
  uint32_t x0 = 0u, x1 = i;
  tf2x32(k0, k1, x0, x1);
  return x0 ^ x1;
#else
  const uint32_t half = (uint32_t)(KK * NN) / 2u;
  uint32_t x0, x1;
  if (i < half) { x0 = i; x1 = i + half; tf2x32(k0, k1, x0, x1); return x0; }
  else          { x0 = i - half; x1 = i; tf2x32(k0, k1, x0, x1); return x1; }
#endif
}

// ---------------- K0: fold resize weights + init inverse mask map
__global__ void k0_fold(const float* __restrict__ w_r1, const float* __restrict__ b_r1,
                        const float* __restrict__ w_r2, const float* __restrict__ b_r2,
                        float* __restrict__ ws) {
  int c = blockIdx.x;      // 0..255
  int co = threadIdx.x;    // 0..63
  float acc = 0.f;
  for (int f = 0; f < 128; ++f)
    acc += w_r1[c * 128 + f] * w_r2[f * 64 + co];
  ws[OFF_WF + c * 64 + co] = acc;
  if (blockIdx.x == 0) {
    float bb = b_r2[co];
    for (int f = 0; f < 128; ++f) bb += b_r1[f] * w_r2[f * 64 + co];
    ws[OFF_BF + co] = bb;
  }
  int* inv = (int*)(ws + OFF_INV);
  int t = blockIdx.x * 64 + threadIdx.x;       // 0..16383
  inv[t] = -1;
  inv[t + BS * FLAT / 2] = -1;
}

// ---------------- K1: 32 threads per n: xi, prob/logp, xi1, inv map
__global__ __launch_bounds__(256) void k1_xi(
    const float* __restrict__ input, const int* __restrict__ midx,
    const float* __restrict__ w_ne1, const float* __restrict__ b_ne1,
    const float* __restrict__ g_ne,  const float* __restrict__ be_ne,
    const float* __restrict__ w_ne2, const float* __restrict__ b_ne2,
    const float* __restrict__ w_p1,  const float* __restrict__ g_p1,
    float* __restrict__ ws) {
  int tid = threadIdx.x;
  int j = tid & 31, nl = tid >> 5;             // 8 n per block
  int bn = blockIdx.x * 8 + nl;                // grid = BS*NN/8 = 512
  int b = bn >> 11, n = bn & (NN - 1);
  int pos = midx[b * NN + n];
  __shared__ float xis[8][66];
  float d = expf((float)(2 * j) * PE_SCALE);
  float ang = (float)pos * d;
  float xs = sinf(ang) + input[((size_t)(b * CC + 2 * j)) * FLAT + pos];
  float xc = cosf(ang) + input[((size_t)(b * CC + 2 * j + 1)) * FLAT + pos];
  xis[nl][2 * j] = xs; xis[nl][2 * j + 1] = xc;
  float2 v2; v2.x = xs; v2.y = xc;
  ((float2*)(ws + OFF_XI + (size_t)(b * NN + n) * CC))[j] = v2;
  __syncthreads();
  float zne = b_ne1[j];
  float z1 = 0.f;
#pragma unroll
  for (int c2 = 0; c2 < CC; ++c2) {
    float xv = xis[nl][c2];
    zne += xv * w_ne1[c2 * 32 + j];
    z1  += xv * w_p1[c2 * 32 + j];
  }
  float ane = g_ne[j] / sqrtf(1.f + EPSBN);
  float h = fmaxf(0.f, zne * ane + be_ne[j]);
  float pp = h * w_ne2[j];
  for (int off = 16; off > 0; off >>= 1) pp += __shfl_down(pp, off, 32);
  if (j == 0) {
    float prob = 1.f / (1.f + expf(-(pp + b_ne2[0])));
    ws[OFF_PROB + b * NN + n] = prob;
    ws[OFF_LOGP + b * NN + n] = logf(prob);
    ((int*)(ws + OFF_INV))[b * FLAT + pos] = n;
  }
  float a1 = g_p1[j] / sqrtf(1.f + EPSBN);
  ws[OFF_XI1 + (size_t)(b * NN + n) * 32 + j] = z1 * a1;
}

// ---------------- K2: categorical draw k for sample b; emit tf, ne_k, m1
__global__ __launch_bounds__(256) void k2_sample(
    const int* __restrict__ midx,
    const float* __restrict__ w_p1, const float* __restrict__ b_p1,
    const float* __restrict__ g_p1, const float* __restrict__ be_p1,
    float* __restrict__ ws) {
  int b = blockIdx.x >> 8, k = blockIdx.x & 255;
  int tid = threadIdx.x;
  uint32_t kb0, kb1;
  jax_key(b, kb0, kb1);
  const float* logp = ws + OFF_LOGP + b * NN;
  const float NEGINF = -__builtin_inff();
  float bv = NEGINF; int bn = NN;
#pragma unroll 1
  for (int r = 0; r < 8; ++r) {
    int n = r * 256 + tid;
    uint32_t bits = jax_bits(kb0, kb1, (uint32_t)(k * NN + n));
    float f = __uint_as_float(0x3f800000u | (bits >> 9)) - 1.0f;
    float u = fmaxf(TINYF, f + TINYF);
    float gmb = -logf(-logf(u));
    float v = logp[n] + gmb;
    if (v > bv || (v == bv && n < bn)) { bv = v; bn = n; }
  }
  __shared__ float sv[256];
  __shared__ int   sn[256];
  __shared__ float mpe[CC];
  sv[tid] = bv; sn[tid] = bn;
  __syncthreads();
  for (int s = 128; s > 0; s >>= 1) {
    if (tid < s) {
      float v2 = sv[tid + s]; int n2 = sn[tid + s];
      if (v2 > sv[tid] || (v2 == sv[tid] && n2 < sn[tid])) { sv[tid] = v2; sn[tid] = n2; }
    }
    __syncthreads();
  }
  int best = sn[0];
  if (tid == 0)
    ws[OFF_NEK + b * KK + k] = ws[OFF_PROB + b * NN + best];
  if (tid < CC) {
    int c = tid;
    ws[OFF_TF + (size_t)(b * KK + k) * CC + c] =
        ws[OFF_XI + (size_t)(b * NN + best) * CC + c];
    int pos = midx[b * NN + best];
    int jj = c >> 1;
    float ang = (float)pos * expf((float)(2 * jj) * PE_SCALE);
    mpe[c] = (c & 1) ? cosf(ang) : sinf(ang);
  }
  __syncthreads();
  if (tid < 32) {
    int jj = tid;
    float acc = b_p1[jj];
#pragma unroll
    for (int c = 0; c < CC; ++c) acc += mpe[c] * w_p1[c * 32 + jj];
    float a = g_p1[jj] / sqrtf(1.f + EPSBN);
    ws[OFF_M1 + (size_t)(b * KK + k) * 32 + jj] = acc * a + be_p1[jj];
  }
}

// ---------------- K3: heavy N x K pairwise MLP (NPB=4, n-paired)
__global__ __launch_bounds__(256, 4) void k3_pair(
    const float* __restrict__ w_p2, const float* __restrict__ b_p2,
    const float* __restrict__ g_p2, const float* __restrict__ be_p2,
    const float* __restrict__ w_p3, const float* __restrict__ b_p3,
    float* __restrict__ ws) {
  __shared__ __align__(16) float w2s[1024];
  __shared__ __align__(16) float PQT[8][256];   // plane-major P values
  __shared__ __align__(16) float xi1s[4][32];
  __shared__ __align__(16) float c2f[32];
  __shared__ __align__(16) float w3l[32];
  __shared__ __align__(16) float xIl[4 * 68], xEl[4 * 68];
  __shared__ float sI[4], sE[4];
  int tid = threadIdx.x;
  int b = blockIdx.x >> 9;                      // grid = BS*NN/4 = 1024
  int n0 = (blockIdx.x & 511) * 4;
  // --- prologue ---
  float m1r[32];
  {
    const float4* m4 = (const float4*)(ws + OFF_M1 + (size_t)(b * KK + tid) * 32);
#pragma unroll
    for (int q = 0; q < 8; ++q) {
      float4 v = m4[q];
      m1r[q * 4 + 0] = v.x; m1r[q * 4 + 1] = v.y;
      m1r[q * 4 + 2] = v.z; m1r[q * 4 + 3] = v.w;
    }
  }
  for (int e = tid; e < 1024; e += 256) {
    int jj = e & 31;
    w2s[e] = w_p2[e] * (g_p2[jj] / sqrtf(1.f + EPSBN));
  }
  if (tid < 32) {
    c2f[tid] = b_p2[tid] * (g_p2[tid] / sqrtf(1.f + EPSBN)) + be_p2[tid];
    w3l[tid] = w_p3[tid];
  }
  if (tid < 128) {
    int nn = tid >> 5, jx = tid & 31;
    xi1s[nn][jx] = ws[OFF_XI1 + (size_t)(b * NN + n0 + nn) * 32 + jx];
  }
  float nekv = ws[OFF_NEK + b * KK + tid];
  float b3 = b_p3[0];
  __syncthreads();
  // --- phase b: per thread k=tid, pairs (p, p+2) share w2 reads ---
  const float4* w2s4 = (const float4*)w2s;
  const float4* c2f4 = (const float4*)c2f;
  const float4* w3l4 = (const float4*)w3l;
#pragma unroll
  for (int p = 0; p < 2; ++p) {
    float z0[32], z1[32];
#pragma unroll
    for (int q = 0; q < 8; ++q) {
      float4 cv = c2f4[q];
      z0[q * 4 + 0] = cv.x; z0[q * 4 + 1] = cv.y; z0[q * 4 + 2] = cv.z; z0[q * 4 + 3] = cv.w;
      z1[q * 4 + 0] = cv.x; z1[q * 4 + 1] = cv.y; z1[q * 4 + 2] = cv.z; z1[q * 4 + 3] = cv.w;
    }
    const float4* x0 = (const float4*)xi1s[p];
    const float4* x1 = (const float4*)xi1s[p + 2];
#pragma unroll
    for (int jq = 0; jq < 8; ++jq) {
      float4 a0 = x0[jq], a1v = x1[jq];
      float xs0[4] = {a0.x, a0.y, a0.z, a0.w};
      float xs1[4] = {a1v.x, a1v.y, a1v.z, a1v.w};
#pragma unroll
      for (int u = 0; u < 4; ++u) {
        int jj = jq * 4 + u;
        float h0 = fmaxf(0.f, xs0[u] + m1r[jj]);
        float h1 = fmaxf(0.f, xs1[u] + m1r[jj]);
#pragma unroll
        for (int q4 = 0; q4 < 8; ++q4) {
          float4 w = w2s4[jj * 8 + q4];
          z0[q4 * 4 + 0] += h0 * w.x; z0[q4 * 4 + 1] += h0 * w.y;
          z0[q4 * 4 + 2] += h0 * w.z; z0[q4 * 4 + 3] += h0 * w.w;
          z1[q4 * 4 + 0] += h1 * w.x; z1[q4 * 4 + 1] += h1 * w.y;
          z1[q4 * 4 + 2] += h1 * w.z; z1[q4 * 4 + 3] += h1 * w.w;
        }
      }
    }
    float zp0 = b3, zp1 = b3;
#pragma unroll
    for (int q = 0; q < 8; ++q) {
      float4 w = w3l4[q];
      zp0 += fmaxf(0.f, z0[q * 4 + 0]) * w.x + fmaxf(0.f, z0[q * 4 + 1]) * w.y
           + fmaxf(0.f, z0[q * 4 + 2]) * w.z + fmaxf(0.f, z0[q * 4 + 3]) * w.w;
      zp1 += fmaxf(0.f, z1[q * 4 + 0]) * w.x + fmaxf(0.f, z1[q * 4 + 1]) * w.y
           + fmaxf(0.f, z1[q * 4 + 2]) * w.z + fmaxf(0.f, z1[q * 4 + 3]) * w.w;
    }
    float P0 = 1.f / (1.f + expf(-zp0));
    float P1 = 1.f / (1.f + expf(-zp1));
    // plane(nn) = (nn&1)*4 + (nn>>1)*2 ; nn0=p -> p*4 ; nn1=p+2 -> p*4+2
    PQT[p * 4 + 0][tid] = P0 * nekv;
    PQT[p * 4 + 1][tid] = (1.f - P0) * nekv;
    PQT[p * 4 + 2][tid] = P1 * nekv;
    PQT[p * 4 + 3][tid] = (1.f - P1) * nekv;
  }
  __syncthreads();
  // --- phase b2: per-n sums of Pi/Pe over k ---
  if (tid < 128) {
    int nn = tid >> 5, jx = tid & 31;
    int pi = (nn & 1) * 4 + (nn >> 1) * 2;
    float s1 = 0.f, s2 = 0.f;
#pragma unroll
    for (int t = 0; t < 8; ++t) {
      s1 += PQT[pi][jx + 32 * t];
      s2 += PQT[pi + 1][jx + 32 * t];
    }
    for (int off = 16; off > 0; off >>= 1) {
      s1 += __shfl_down(s1, off, 32);
      s2 += __shfl_down(s2, off, 32);
    }
    if (jx == 0) { sI[nn] = s1; sE[nn] = s2; }
  }
  __syncthreads();
  // --- phase c: x_intra/x_inter, all 256 threads = (n, c) ---
  {
    int c = tid & 63, n = tid >> 6;
    int pip = (n & 1) * 4 + (n >> 1) * 2;
    const float4* PI4 = (const float4*)PQT[pip];
    const float4* PE4 = (const float4*)PQT[pip + 1];
    const float* tfg = ws + OFF_TF + (size_t)b * KK * CC + c;
    float aI = 0.f, aE = 0.f;
#pragma unroll 4
    for (int kq = 0; kq < 64; ++kq) {
      float4 piv = PI4[kq], pev = PE4[kq];
      float t0 = tfg[(4 * kq + 0) * 64];
      float t1 = tfg[(4 * kq + 1) * 64];
      float t2 = tfg[(4 * kq + 2) * 64];
      float t3 = tfg[(4 * kq + 3) * 64];
      aI += piv.x * t0 + piv.y * t1 + piv.z * t2 + piv.w * t3;
      aE += pev.x * t0 + pev.y * t1 + pev.z * t2 + pev.w * t3;
    }
    xIl[n * 68 + c] = aI / sI[n];
    xEl[n * 68 + c] = aE / sE[n];
  }
  __syncthreads();
  // --- phase d: delta = xI @ WF[64:128] + xE @ WF[128:192] ---
  {
    int co = tid & 63, nn = tid >> 6;
    const float4* xI4 = (const float4*)&xIl[nn * 68];
    const float4* xE4 = (const float4*)&xEl[nn * 68];
    const float* wI = ws + OFF_WF + 64 * CC + co;
    const float* wE = ws + OFF_WF + 128 * CC + co;
    float dsum = 0.f;
#pragma unroll 4
    for (int cq = 0; cq < 16; ++cq) {
      float4 xi4 = xI4[cq], xe4 = xE4[cq];
      dsum += xi4.x * wI[(4 * cq + 0) * 64] + xi4.y * wI[(4 * cq + 1) * 64]
            + xi4.z * wI[(4 * cq + 2) * 64] + xi4.w * wI[(4 * cq + 3) * 64];
      dsum += xe4.x * wE[(4 * cq + 0) * 64] + xe4.y * wE[(4 * cq + 1) * 64]
            + xe4.z * wE[(4 * cq + 2) * 64] + xe4.w * wE[(4 * cq + 3) * 64];
    }
    ws[OFF_DELTA + (size_t)(b * NN + n0 + nn) * CC + co] = dsum;
  }
}

// ---------------- K4: base resize + masked delta add, coalesced single store
__global__ __launch_bounds__(256) void k4_out(
    const float* __restrict__ input, float* __restrict__ out,
    const float* __restrict__ ws) {
  __shared__ __align__(16) float wfa[64 * 64];
  __shared__ float bfl[64];
  int tid = threadIdx.x;
  const float* wf = ws + OFF_WF;
  for (int e = tid; e < 4096; e += 256) {
    int c = e >> 6, co = e & 63;
    wfa[e] = wf[c * 64 + co] + wf[(192 + c) * 64 + co];
  }
  if (tid < 64) bfl[tid] = ws[OFF_BF + tid];
  __syncthreads();
  int q = tid >> 6, lane = tid & 63;
  int pg = blockIdx.x * 64 + lane;             // grid = BS*FLAT/64 = 512
  int b = pg >> 14, pos = pg & (FLAT - 1);
  const int* inv = (const int*)(ws + OFF_INV);
  float acc[16];
#pragma unroll
  for (int u = 0; u < 16; ++u) acc[u] = bfl[q * 16 + u];
#pragma unroll 4
  for (int c = 0; c < 64; ++c) {
    float xv = input[((size_t)(b * CC + c)) * FLAT + pos];
    const float4* wr = (const float4*)&wfa[c * 64 + q * 16];
#pragma unroll
    for (int u4 = 0; u4 < 4; ++u4) {
      float4 w = wr[u4];
      acc[u4 * 4 + 0] += xv * w.x; acc[u4 * 4 + 1] += xv * w.y;
      acc[u4 * 4 + 2] += xv * w.z; acc[u4 * 4 + 3] += xv * w.w;
    }
  }
  int n = inv[pg];
  if (n >= 0) {
    const float4* dr = (const float4*)(ws + OFF_DELTA + (size_t)(b * NN + n) * CC + q * 16);
#pragma unroll
    for (int u4 = 0; u4 < 4; ++u4) {
      float4 dv = dr[u4];
      acc[u4 * 4 + 0] += dv.x; acc[u4 * 4 + 1] += dv.y;
      acc[u4 * 4 + 2] += dv.z; acc[u4 * 4 + 3] += dv.w;
    }
  }
#pragma unroll
  for (int u = 0; u < 16; ++u)
    out[((size_t)(b * CC + q * 16 + u)) * FLAT + pos] = acc[u];
}

// ---------------- launch ----------------
extern "C" void kernel_launch(void* const* d_in, const int* in_sizes, int n_in,
                              void* d_out, int out_size, void* d_ws, size_t ws_size,
                              hipStream_t stream) {
  const float* input = (const float*)d_in[0];
  const int*   midx  = (const int*)  d_in[1];
  const float* w_ne1 = (const float*)d_in[2];
  const float* b_ne1 = (const float*)d_in[3];
  const float* g_ne  = (const float*)d_in[4];
  const float* be_ne = (const float*)d_in[5];
  const float* w_ne2 = (const float*)d_in[6];
  const float* b_ne2 = (const float*)d_in[7];
  const float* w_p1  = (const float*)d_in[8];
  const float* b_p1  = (const float*)d_in[9];
  const float* g_p1  = (const float*)d_in[10];
  const float* be_p1 = (const float*)d_in[11];
  const float* w_p2  = (const float*)d_in[12];
  const float* b_p2  = (const float*)d_in[13];
  const float* g_p2  = (const float*)d_in[14];
  const float* be_p2 = (const float*)d_in[15];
  const float* w_p3  = (const float*)d_in[16];
  const float* b_p3  = (const float*)d_in[17];
  const float* w_r1  = (const float*)d_in[18];
  const float* b_r1  = (const float*)d_in[19];
  const float* w_r2  = (const float*)d_in[20];
  const float* b_r2  = (const float*)d_in[21];
  float* out = (float*)d_out;
  float* ws  = (float*)d_ws;

  k0_fold<<<dim3(256), dim3(64), 0, stream>>>(w_r1, b_r1, w_r2, b_r2, ws);
  k1_xi<<<dim3(BS * NN / 8), dim3(256), 0, stream>>>(
      input, midx, w_ne1, b_ne1, g_ne, be_ne, w_ne2, b_ne2, w_p1, g_p1, ws);
  k2_sample<<<dim3(BS * KK), dim3(256), 0, stream>>>(
      midx, w_p1, b_p1, g_p1, be_p1, ws);
  k3_pair<<<dim3(BS * NN / 4), dim3(256), 0, stream>>>(
      w_p2, b_p2, g_p2, be_p2, w_p3, b_p3, ws);
  k4_out<<<dim3(BS * FLAT / 64), dim3(256), 0, stream>>>(input, out, ws);
}

// Round 7
// 384.245 us; speedup vs baseline: 1.4287x; 1.4287x over previous
//
#include <hip/hip_runtime.h>
#include <cstdint>
#include <cmath>

// ---------------- problem constants ----------------
#define BS    2
#define CC    64
#define FLAT  16384
#define NN    2048
#define KK    256
#define EPSBN 1e-5f
#define TINYF 1.17549435e-38f
#define PE_SCALE -0.14391156831212787f
#define JAX_PARTITIONABLE 1

// ---------------- workspace layout (float offsets) ----------------
#define OFF_XI    0                          // [BS][NN][CC]
#define OFF_XI1   (OFF_XI   + BS*NN*CC)      // [BS][NN][32]
#define OFF_PROB  (OFF_XI1  + BS*NN*32)      // [BS][NN]
#define OFF_LOGP  (OFF_PROB + BS*NN)         // [BS][NN]
#define OFF_NEK   (OFF_LOGP + BS*NN)         // [BS][KK]
#define OFF_TF    (OFF_NEK  + BS*KK)         // [BS][KK][CC]
#define OFF_M1    (OFF_TF   + BS*KK*CC)      // [BS][KK][32]
#define OFF_DELTA (OFF_M1   + BS*KK*32)      // [BS][NN][CC]
#define OFF_WF    (OFF_DELTA+ BS*NN*CC)      // [256][64]
#define OFF_BF    (OFF_WF   + 256*CC)        // [64]
#define OFF_INV   (OFF_BF   + CC)            // [BS][FLAT] ints

// ---------------- threefry2x32 ----------------
__device__ __forceinline__ uint32_t rotl32(uint32_t x, int r) {
  return (x << r) | (x >> (32 - r));
}
__device__ __forceinline__ void tf2x32(uint32_t k0, uint32_t k1,
                                       uint32_t& x0, uint32_t& x1) {
  uint32_t k2 = k0 ^ k1 ^ 0x1BD11BDAu;
  x0 += k0; x1 += k1;
#define TFR(r) { x0 += x1; x1 = rotl32(x1, r); x1 ^= x0; }
  TFR(13) TFR(15) TFR(26) TFR(6)  x0 += k1; x1 += k2 + 1u;
  TFR(17) TFR(29) TFR(16) TFR(24) x0 += k2; x1 += k0 + 2u;
  TFR(13) TFR(15) TFR(26) TFR(6)  x0 += k0; x1 += k1 + 3u;
  TFR(17) TFR(29) TFR(16) TFR(24) x0 += k1; x1 += k2 + 4u;
  TFR(13) TFR(15) TFR(26) TFR(6)  x0 += k2; x1 += k0 + 5u;
#undef TFR
}
__device__ __forceinline__ void jax_key(int b, uint32_t& k0, uint32_t& k1) {
#if JAX_PARTITIONABLE
  uint32_t x0 = 0u, x1 = (uint32_t)b;
  tf2x32(0u, 42u, x0, x1);
  k0 = x0; k1 = x1;
#else
  uint32_t a0 = 0u, a1 = 2u, c0 = 1u, c1 = 3u;
  tf2x32(0u, 42u, a0, a1);
  tf2x32(0u, 42u, c0, c1);
  if (b == 0) { k0 = a0; k1 = c0; } else { k0 = a1; k1 = c1; }
#endif
}
__device__ __forceinline__ uint32_t jax_bits(uint32_t k0, uint32_t k1, uint32_t i) {
#if JAX_PARTITIONABLE
  uint32_t x0 = 0u, x1 = i;
  tf2x32(k0, k1, x0, x1);
  return x0 ^ x1;
#else
  const uint32_t half = (uint32_t)(KK * NN) / 2u;
  uint32_t x0, x1;
  if (i < half) { x0 = i; x1 = i + half; tf2x32(k0, k1, x0, x1); return x0; }
  else          { x0 = i - half; x1 = i; tf2x32(k0, k1, x0, x1); return x1; }
#endif
}

// ---------------- K0: fold resize weights + init inverse mask map
__global__ void k0_fold(const float* __restrict__ w_r1, const float* __restrict__ b_r1,
                        const float* __restrict__ w_r2, const float* __restrict__ b_r2,
                        float* __restrict__ ws) {
  int c = blockIdx.x;      // 0..255
  int co = threadIdx.x;    // 0..63
  float acc = 0.f;
  for (int f = 0; f < 128; ++f)
    acc += w_r1[c * 128 + f] * w_r2[f * 64 + co];
  ws[OFF_WF + c * 64 + co] = acc;
  if (blockIdx.x == 0) {
    float bb = b_r2[co];
    for (int f = 0; f < 128; ++f) bb += b_r1[f] * w_r2[f * 64 + co];
    ws[OFF_BF + co] = bb;
  }
  int* inv = (int*)(ws + OFF_INV);
  int t = blockIdx.x * 64 + threadIdx.x;       // 0..16383
  inv[t] = -1;
  inv[t + BS * FLAT / 2] = -1;
}

// ---------------- K1: 32 threads per n: xi, prob/logp, xi1, inv map
__global__ __launch_bounds__(256) void k1_xi(
    const float* __restrict__ input, const int* __restrict__ midx,
    const float* __restrict__ w_ne1, const float* __restrict__ b_ne1,
    const float* __restrict__ g_ne,  const float* __restrict__ be_ne,
    const float* __restrict__ w_ne2, const float* __restrict__ b_ne2,
    const float* __restrict__ w_p1,  const float* __restrict__ g_p1,
    float* __restrict__ ws) {
  int tid = threadIdx.x;
  int j = tid & 31, nl = tid >> 5;             // 8 n per block
  int bn = blockIdx.x * 8 + nl;                // grid = BS*NN/8 = 512
  int b = bn >> 11, n = bn & (NN - 1);
  int pos = midx[b * NN + n];
  __shared__ float xis[8][66];
  float d = expf((float)(2 * j) * PE_SCALE);
  float ang = (float)pos * d;
  float xs = sinf(ang) + input[((size_t)(b * CC + 2 * j)) * FLAT + pos];
  float xc = cosf(ang) + input[((size_t)(b * CC + 2 * j + 1)) * FLAT + pos];
  xis[nl][2 * j] = xs; xis[nl][2 * j + 1] = xc;
  float2 v2; v2.x = xs; v2.y = xc;
  ((float2*)(ws + OFF_XI + (size_t)(b * NN + n) * CC))[j] = v2;
  __syncthreads();
  float zne = b_ne1[j];
  float z1 = 0.f;
#pragma unroll
  for (int c2 = 0; c2 < CC; ++c2) {
    float xv = xis[nl][c2];
    zne += xv * w_ne1[c2 * 32 + j];
    z1  += xv * w_p1[c2 * 32 + j];
  }
  float ane = g_ne[j] / sqrtf(1.f + EPSBN);
  float h = fmaxf(0.f, zne * ane + be_ne[j]);
  float pp = h * w_ne2[j];
  for (int off = 16; off > 0; off >>= 1) pp += __shfl_down(pp, off, 32);
  if (j == 0) {
    float prob = 1.f / (1.f + expf(-(pp + b_ne2[0])));
    ws[OFF_PROB + b * NN + n] = prob;
    ws[OFF_LOGP + b * NN + n] = logf(prob);
    ((int*)(ws + OFF_INV))[b * FLAT + pos] = n;
  }
  float a1 = g_p1[j] / sqrtf(1.f + EPSBN);
  ws[OFF_XI1 + (size_t)(b * NN + n) * 32 + j] = z1 * a1;
}

// ---------------- K2: categorical draw k for sample b; emit tf, ne_k, m1
__global__ __launch_bounds__(256) void k2_sample(
    const int* __restrict__ midx,
    const float* __restrict__ w_p1, const float* __restrict__ b_p1,
    const float* __restrict__ g_p1, const float* __restrict__ be_p1,
    float* __restrict__ ws) {
  int b = blockIdx.x >> 8, k = blockIdx.x & 255;
  int tid = threadIdx.x;
  uint32_t kb0, kb1;
  jax_key(b, kb0, kb1);
  const float* logp = ws + OFF_LOGP + b * NN;
  const float NEGINF = -__builtin_inff();
  float bv = NEGINF; int bn = NN;
#pragma unroll 1
  for (int r = 0; r < 8; ++r) {
    int n = r * 256 + tid;
    uint32_t bits = jax_bits(kb0, kb1, (uint32_t)(k * NN + n));
    float f = __uint_as_float(0x3f800000u | (bits >> 9)) - 1.0f;
    float u = fmaxf(TINYF, f + TINYF);
    float gmb = -logf(-logf(u));
    float v = logp[n] + gmb;
    if (v > bv || (v == bv && n < bn)) { bv = v; bn = n; }
  }
  __shared__ float sv[256];
  __shared__ int   sn[256];
  __shared__ float mpe[CC];
  sv[tid] = bv; sn[tid] = bn;
  __syncthreads();
  for (int s = 128; s > 0; s >>= 1) {
    if (tid < s) {
      float v2 = sv[tid + s]; int n2 = sn[tid + s];
      if (v2 > sv[tid] || (v2 == sv[tid] && n2 < sn[tid])) { sv[tid] = v2; sn[tid] = n2; }
    }
    __syncthreads();
  }
  int best = sn[0];
  if (tid == 0)
    ws[OFF_NEK + b * KK + k] = ws[OFF_PROB + b * NN + best];
  if (tid < CC) {
    int c = tid;
    ws[OFF_TF + (size_t)(b * KK + k) * CC + c] =
        ws[OFF_XI + (size_t)(b * NN + best) * CC + c];
    int pos = midx[b * NN + best];
    int jj = c >> 1;
    float ang = (float)pos * expf((float)(2 * jj) * PE_SCALE);
    mpe[c] = (c & 1) ? cosf(ang) : sinf(ang);
  }
  __syncthreads();
  if (tid < 32) {
    int jj = tid;
    float acc = b_p1[jj];
#pragma unroll
    for (int c = 0; c < CC; ++c) acc += mpe[c] * w_p1[c * 32 + jj];
    float a = g_p1[jj] / sqrtf(1.f + EPSBN);
    ws[OFF_M1 + (size_t)(b * KK + k) * 32 + jj] = acc * a + be_p1[jj];
  }
}

// ---------------- K3: heavy N x K pairwise MLP (NPB=4, n-paired)
// __launch_bounds__(256, 2): VGPR cap 256. (256,4) capped at 64 VGPR and
// spilled ~1.27 GB/dispatch to scratch (round-4 counters) — never again.
__global__ __launch_bounds__(256, 2) void k3_pair(
    const float* __restrict__ w_p2, const float* __restrict__ b_p2,
    const float* __restrict__ g_p2, const float* __restrict__ be_p2,
    const float* __restrict__ w_p3, const float* __restrict__ b_p3,
    float* __restrict__ ws) {
  __shared__ __align__(16) float w2s[1024];
  __shared__ __align__(16) float PQT[8][256];   // plane-major P values
  __shared__ __align__(16) float xi1s[4][32];
  __shared__ __align__(16) float c2f[32];
  __shared__ __align__(16) float w3l[32];
  __shared__ __align__(16) float xIl[4 * 68], xEl[4 * 68];
  __shared__ float sI[4], sE[4];
  int tid = threadIdx.x;
  int b = blockIdx.x >> 9;                      // grid = BS*NN/4 = 1024
  int n0 = (blockIdx.x & 511) * 4;
  // --- prologue ---
  float m1r[32];
  {
    const float4* m4 = (const float4*)(ws + OFF_M1 + (size_t)(b * KK + tid) * 32);
#pragma unroll
    for (int q = 0; q < 8; ++q) {
      float4 v = m4[q];
      m1r[q * 4 + 0] = v.x; m1r[q * 4 + 1] = v.y;
      m1r[q * 4 + 2] = v.z; m1r[q * 4 + 3] = v.w;
    }
  }
  for (int e = tid; e < 1024; e += 256) {
    int jj = e & 31;
    w2s[e] = w_p2[e] * (g_p2[jj] / sqrtf(1.f + EPSBN));
  }
  if (tid < 32) {
    c2f[tid] = b_p2[tid] * (g_p2[tid] / sqrtf(1.f + EPSBN)) + be_p2[tid];
    w3l[tid] = w_p3[tid];
  }
  if (tid < 128) {
    int nn = tid >> 5, jx = tid & 31;
    xi1s[nn][jx] = ws[OFF_XI1 + (size_t)(b * NN + n0 + nn) * 32 + jx];
  }
  float nekv = ws[OFF_NEK + b * KK + tid];
  float b3 = b_p3[0];
  __syncthreads();
  // --- phase b: per thread k=tid, pairs (p, p+2) share w2 reads ---
  const float4* w2s4 = (const float4*)w2s;
  const float4* c2f4 = (const float4*)c2f;
  const float4* w3l4 = (const float4*)w3l;
#pragma unroll
  for (int p = 0; p < 2; ++p) {
    float z0[32], z1[32];
#pragma unroll
    for (int q = 0; q < 8; ++q) {
      float4 cv = c2f4[q];
      z0[q * 4 + 0] = cv.x; z0[q * 4 + 1] = cv.y; z0[q * 4 + 2] = cv.z; z0[q * 4 + 3] = cv.w;
      z1[q * 4 + 0] = cv.x; z1[q * 4 + 1] = cv.y; z1[q * 4 + 2] = cv.z; z1[q * 4 + 3] = cv.w;
    }
    const float4* x0 = (const float4*)xi1s[p];
    const float4* x1 = (const float4*)xi1s[p + 2];
#pragma unroll
    for (int jq = 0; jq < 8; ++jq) {
      float4 a0 = x0[jq], a1v = x1[jq];
      float xs0[4] = {a0.x, a0.y, a0.z, a0.w};
      float xs1[4] = {a1v.x, a1v.y, a1v.z, a1v.w};
#pragma unroll
      for (int u = 0; u < 4; ++u) {
        int jj = jq * 4 + u;
        float h0 = fmaxf(0.f, xs0[u] + m1r[jj]);
        float h1 = fmaxf(0.f, xs1[u] + m1r[jj]);
#pragma unroll
        for (int q4 = 0; q4 < 8; ++q4) {
          float4 w = w2s4[jj * 8 + q4];
          z0[q4 * 4 + 0] += h0 * w.x; z0[q4 * 4 + 1] += h0 * w.y;
          z0[q4 * 4 + 2] += h0 * w.z; z0[q4 * 4 + 3] += h0 * w.w;
          z1[q4 * 4 + 0] += h1 * w.x; z1[q4 * 4 + 1] += h1 * w.y;
          z1[q4 * 4 + 2] += h1 * w.z; z1[q4 * 4 + 3] += h1 * w.w;
        }
      }
    }
    float zp0 = b3, zp1 = b3;
#pragma unroll
    for (int q = 0; q < 8; ++q) {
      float4 w = w3l4[q];
      zp0 += fmaxf(0.f, z0[q * 4 + 0]) * w.x + fmaxf(0.f, z0[q * 4 + 1]) * w.y
           + fmaxf(0.f, z0[q * 4 + 2]) * w.z + fmaxf(0.f, z0[q * 4 + 3]) * w.w;
      zp1 += fmaxf(0.f, z1[q * 4 + 0]) * w.x + fmaxf(0.f, z1[q * 4 + 1]) * w.y
           + fmaxf(0.f, z1[q * 4 + 2]) * w.z + fmaxf(0.f, z1[q * 4 + 3]) * w.w;
    }
    float P0 = 1.f / (1.f + expf(-zp0));
    float P1 = 1.f / (1.f + expf(-zp1));
    // plane(nn) = (nn&1)*4 + (nn>>1)*2 ; nn0=p -> p*4 ; nn1=p+2 -> p*4+2
    PQT[p * 4 + 0][tid] = P0 * nekv;
    PQT[p * 4 + 1][tid] = (1.f - P0) * nekv;
    PQT[p * 4 + 2][tid] = P1 * nekv;
    PQT[p * 4 + 3][tid] = (1.f - P1) * nekv;
  }
  __syncthreads();
  // --- phase b2: per-n sums of Pi/Pe over k ---
  if (tid < 128) {
    int nn = tid >> 5, jx = tid & 31;
    int pi = (nn & 1) * 4 + (nn >> 1) * 2;
    float s1 = 0.f, s2 = 0.f;
#pragma unroll
    for (int t = 0; t < 8; ++t) {
      s1 += PQT[pi][jx + 32 * t];
      s2 += PQT[pi + 1][jx + 32 * t];
    }
    for (int off = 16; off > 0; off >>= 1) {
      s1 += __shfl_down(s1, off, 32);
      s2 += __shfl_down(s2, off, 32);
    }
    if (jx == 0) { sI[nn] = s1; sE[nn] = s2; }
  }
  __syncthreads();
  // --- phase c: x_intra/x_inter, all 256 threads = (n, c) ---
  {
    int c = tid & 63, n = tid >> 6;
    int pip = (n & 1) * 4 + (n >> 1) * 2;
    const float4* PI4 = (const float4*)PQT[pip];
    const float4* PE4 = (const float4*)PQT[pip + 1];
    const float* tfg = ws + OFF_TF + (size_t)b * KK * CC + c;
    float aI = 0.f, aE = 0.f;
#pragma unroll 4
    for (int kq = 0; kq < 64; ++kq) {
      float4 piv = PI4[kq], pev = PE4[kq];
      float t0 = tfg[(4 * kq + 0) * 64];
      float t1 = tfg[(4 * kq + 1) * 64];
      float t2 = tfg[(4 * kq + 2) * 64];
      float t3 = tfg[(4 * kq + 3) * 64];
      aI += piv.x * t0 + piv.y * t1 + piv.z * t2 + piv.w * t3;
      aE += pev.x * t0 + pev.y * t1 + pev.z * t2 + pev.w * t3;
    }
    xIl[n * 68 + c] = aI / sI[n];
    xEl[n * 68 + c] = aE / sE[n];
  }
  __syncthreads();
  // --- phase d: delta = xI @ WF[64:128] + xE @ WF[128:192] ---
  {
    int co = tid & 63, nn = tid >> 6;
    const float4* xI4 = (const float4*)&xIl[nn * 68];
    const float4* xE4 = (const float4*)&xEl[nn * 68];
    const float* wI = ws + OFF_WF + 64 * CC + co;
    const float* wE = ws + OFF_WF + 128 * CC + co;
    float dsum = 0.f;
#pragma unroll 4
    for (int cq = 0; cq < 16; ++cq) {
      float4 xi4 = xI4[cq], xe4 = xE4[cq];
      dsum += xi4.x * wI[(4 * cq + 0) * 64] + xi4.y * wI[(4 * cq + 1) * 64]
            + xi4.z * wI[(4 * cq + 2) * 64] + xi4.w * wI[(4 * cq + 3) * 64];
      dsum += xe4.x * wE[(4 * cq + 0) * 64] + xe4.y * wE[(4 * cq + 1) * 64]
            + xe4.z * wE[(4 * cq + 2) * 64] + xe4.w * wE[(4 * cq + 3) * 64];
    }
    ws[OFF_DELTA + (size_t)(b * NN + n0 + nn) * CC + co] = dsum;
  }
}

// ---------------- K4: base resize + masked delta add, coalesced single store
__global__ __launch_bounds__(256) void k4_out(
    const float* __restrict__ input, float* __restrict__ out,
    const float* __restrict__ ws) {
  __shared__ __align__(16) float wfa[64 * 64];
  __shared__ float bfl[64];
  int tid = threadIdx.x;
  const float* wf = ws + OFF_WF;
  for (int e = tid; e < 4096; e += 256) {
    int c = e >> 6, co = e & 63;
    wfa[e] = wf[c * 64 + co] + wf[(192 + c) * 64 + co];
  }
  if (tid < 64) bfl[tid] = ws[OFF_BF + tid];
  __syncthreads();
  int q = tid >> 6, lane = tid & 63;
  int pg = blockIdx.x * 64 + lane;             // grid = BS*FLAT/64 = 512
  int b = pg >> 14, pos = pg & (FLAT - 1);
  const int* inv = (const int*)(ws + OFF_INV);
  float acc[16];
#pragma unroll
  for (int u = 0; u < 16; ++u) acc[u] = bfl[q * 16 + u];
#pragma unroll 4
  for (int c = 0; c < 64; ++c) {
    float xv = input[((size_t)(b * CC + c)) * FLAT + pos];
    const float4* wr = (const float4*)&wfa[c * 64 + q * 16];
#pragma unroll
    for (int u4 = 0; u4 < 4; ++u4) {
      float4 w = wr[u4];
      acc[u4 * 4 + 0] += xv * w.x; acc[u4 * 4 + 1] += xv * w.y;
      acc[u4 * 4 + 2] += xv * w.z; acc[u4 * 4 + 3] += xv * w.w;
    }
  }
  int n = inv[pg];
  if (n >= 0) {
    const float4* dr = (const float4*)(ws + OFF_DELTA + (size_t)(b * NN + n) * CC + q * 16);
#pragma unroll
    for (int u4 = 0; u4 < 4; ++u4) {
      float4 dv = dr[u4];
      acc[u4 * 4 + 0] += dv.x; acc[u4 * 4 + 1] += dv.y;
      acc[u4 * 4 + 2] += dv.z; acc[u4 * 4 + 3] += dv.w;
    }
  }
#pragma unroll
  for (int u = 0; u < 16; ++u)
    out[((size_t)(b * CC + q * 16 + u)) * FLAT + pos] = acc[u];
}

// ---------------- launch ----------------
extern "C" void kernel_launch(void* const* d_in, const int* in_sizes, int n_in,
                              void* d_out, int out_size, void* d_ws, size_t ws_size,
                              hipStream_t stream) {
  const float* input = (const float*)d_in[0];
  const int*   midx  = (const int*)  d_in[1];
  const float* w_ne1 = (const float*)d_in[2];
  const float* b_ne1 = (const float*)d_in[3];
  const float* g_ne  = (const float*)d_in[4];
  const float* be_ne = (const float*)d_in[5];
  const float* w_ne2 = (const float*)d_in[6];
  const float* b_ne2 = (const float*)d_in[7];
  const float* w_p1  = (const float*)d_in[8];
  const float* b_p1  = (const float*)d_in[9];
  const float* g_p1  = (const float*)d_in[10];
  const float* be_p1 = (const float*)d_in[11];
  const float* w_p2  = (const float*)d_in[12];
  const float* b_p2  = (const float*)d_in[13];
  const float* g_p2  = (const float*)d_in[14];
  const float* be_p2 = (const float*)d_in[15];
  const float* w_p3  = (const float*)d_in[16];
  const float* b_p3  = (const float*)d_in[17];
  const float* w_r1  = (const float*)d_in[18];
  const float* b_r1  = (const float*)d_in[19];
  const float* w_r2  = (const float*)d_in[20];
  const float* b_r2  = (const float*)d_in[21];
  float* out = (float*)d_out;
  float* ws  = (float*)d_ws;

  k0_fold<<<dim3(256), dim3(64), 0, stream>>>(w_r1, b_r1, w_r2, b_r2, ws);
  k1_xi<<<dim3(BS * NN / 8), dim3(256), 0, stream>>>(
      input, midx, w_ne1, b_ne1, g_ne, be_ne, w_ne2, b_ne2, w_p1, g_p1, ws);
  k2_sample<<<dim3(BS * KK), dim3(256), 0, stream>>>(
      midx, w_p1, b_p1, g_p1, be_p1, ws);
  k3_pair<<<dim3(BS * NN / 4), dim3(256), 0, stream>>>(
      w_p2, b_p2, g_p2, be_p2, w_p3, b_p3, ws);
  k4_out<<<dim3(BS * FLAT / 64), dim3(256), 0, stream>>>(input, out, ws);
}

// Round 8
// 192.148 us; speedup vs baseline: 2.8570x; 1.9997x over previous
//
#include <hip/hip_runtime.h>
#include <cstdint>
#include <cmath>

// ---------------- problem constants ----------------
#define BS    2
#define CC    64
#define FLAT  16384
#define NN    2048
#define KK    256
#define EPSBN 1e-5f
#define TINYF 1.17549435e-38f
#define PE_SCALE -0.14391156831212787f
#define JAX_PARTITIONABLE 1

// ---------------- workspace layout (float offsets) ----------------
#define OFF_XI    0                          // [BS][NN][CC]
#define OFF_XI1   (OFF_XI   + BS*NN*CC)      // [BS][NN][32]
#define OFF_PROB  (OFF_XI1  + BS*NN*32)      // [BS][NN]
#define OFF_LOGP  (OFF_PROB + BS*NN)         // [BS][NN]
#define OFF_NEK   (OFF_LOGP + BS*NN)         // [BS][KK]
#define OFF_TF    (OFF_NEK  + BS*KK)         // [BS][KK][CC]
#define OFF_M1    (OFF_TF   + BS*KK*CC)      // [BS][KK][32]
#define OFF_DELTA (OFF_M1   + BS*KK*32)      // [BS][NN][CC]
#define OFF_WF    (OFF_DELTA+ BS*NN*CC)      // [256][64]
#define OFF_BF    (OFF_WF   + 256*CC)        // [64]
#define OFF_INV   (OFF_BF   + CC)            // [BS][FLAT] ints

// ---------------- threefry2x32 ----------------
__device__ __forceinline__ uint32_t rotl32(uint32_t x, int r) {
  return (x << r) | (x >> (32 - r));
}
__device__ __forceinline__ void tf2x32(uint32_t k0, uint32_t k1,
                                       uint32_t& x0, uint32_t& x1) {
  uint32_t k2 = k0 ^ k1 ^ 0x1BD11BDAu;
  x0 += k0; x1 += k1;
#define TFR(r) { x0 += x1; x1 = rotl32(x1, r); x1 ^= x0; }
  TFR(13) TFR(15) TFR(26) TFR(6)  x0 += k1; x1 += k2 + 1u;
  TFR(17) TFR(29) TFR(16) TFR(24) x0 += k2; x1 += k0 + 2u;
  TFR(13) TFR(15) TFR(26) TFR(6)  x0 += k0; x1 += k1 + 3u;
  TFR(17) TFR(29) TFR(16) TFR(24) x0 += k1; x1 += k2 + 4u;
  TFR(13) TFR(15) TFR(26) TFR(6)  x0 += k2; x1 += k0 + 5u;
#undef TFR
}
__device__ __forceinline__ void jax_key(int b, uint32_t& k0, uint32_t& k1) {
#if JAX_PARTITIONABLE
  uint32_t x0 = 0u, x1 = (uint32_t)b;
  tf2x32(0u, 42u, x0, x1);
  k0 = x0; k1 = x1;
#else
  uint32_t a0 = 0u, a1 = 2u, c0 = 1u, c1 = 3u;
  tf2x32(0u, 42u, a0, a1);
  tf2x32(0u, 42u, c0, c1);
  if (b == 0) { k0 = a0; k1 = c0; } else { k0 = a1; k1 = c1; }
#endif
}
__device__ __forceinline__ uint32_t jax_bits(uint32_t k0, uint32_t k1, uint32_t i) {
#if JAX_PARTITIONABLE
  uint32_t x0 = 0u, x1 = i;
  tf2x32(k0, k1, x0, x1);
  return x0 ^ x1;
#else
  const uint32_t half = (uint32_t)(KK * NN) / 2u;
  uint32_t x0, x1;
  if (i < half) { x0 = i; x1 = i + half; tf2x32(k0, k1, x0, x1); return x0; }
  else          { x0 = i - half; x1 = i; tf2x32(k0, k1, x0, x1); return x1; }
#endif
}

// ---------------- K0: fold resize weights + init inverse mask map
__global__ void k0_fold(const float* __restrict__ w_r1, const float* __restrict__ b_r1,
                        const float* __restrict__ w_r2, const float* __restrict__ b_r2,
                        float* __restrict__ ws) {
  int c = blockIdx.x;      // 0..255
  int co = threadIdx.x;    // 0..63
  float acc = 0.f;
  for (int f = 0; f < 128; ++f)
    acc += w_r1[c * 128 + f] * w_r2[f * 64 + co];
  ws[OFF_WF + c * 64 + co] = acc;
  if (blockIdx.x == 0) {
    float bb = b_r2[co];
    for (int f = 0; f < 128; ++f) bb += b_r1[f] * w_r2[f * 64 + co];
    ws[OFF_BF + co] = bb;
  }
  int* inv = (int*)(ws + OFF_INV);
  int t = blockIdx.x * 64 + threadIdx.x;       // 0..16383
  inv[t] = -1;
  inv[t + BS * FLAT / 2] = -1;
}

// ---------------- K1: 32 threads per n: xi, prob/logp, xi1, inv map
__global__ __launch_bounds__(256) void k1_xi(
    const float* __restrict__ input, const int* __restrict__ midx,
    const float* __restrict__ w_ne1, const float* __restrict__ b_ne1,
    const float* __restrict__ g_ne,  const float* __restrict__ be_ne,
    const float* __restrict__ w_ne2, const float* __restrict__ b_ne2,
    const float* __restrict__ w_p1,  const float* __restrict__ g_p1,
    float* __restrict__ ws) {
  int tid = threadIdx.x;
  int j = tid & 31, nl = tid >> 5;             // 8 n per block
  int bn = blockIdx.x * 8 + nl;                // grid = BS*NN/8 = 512
  int b = bn >> 11, n = bn & (NN - 1);
  int pos = midx[b * NN + n];
  __shared__ float xis[8][66];
  float d = expf((float)(2 * j) * PE_SCALE);
  float ang = (float)pos * d;
  float xs = sinf(ang) + input[((size_t)(b * CC + 2 * j)) * FLAT + pos];
  float xc = cosf(ang) + input[((size_t)(b * CC + 2 * j + 1)) * FLAT + pos];
  xis[nl][2 * j] = xs; xis[nl][2 * j + 1] = xc;
  float2 v2; v2.x = xs; v2.y = xc;
  ((float2*)(ws + OFF_XI + (size_t)(b * NN + n) * CC))[j] = v2;
  __syncthreads();
  float zne = b_ne1[j];
  float z1 = 0.f;
#pragma unroll
  for (int c2 = 0; c2 < CC; ++c2) {
    float xv = xis[nl][c2];
    zne += xv * w_ne1[c2 * 32 + j];
    z1  += xv * w_p1[c2 * 32 + j];
  }
  float ane = g_ne[j] / sqrtf(1.f + EPSBN);
  float h = fmaxf(0.f, zne * ane + be_ne[j]);
  float pp = h * w_ne2[j];
  for (int off = 16; off > 0; off >>= 1) pp += __shfl_down(pp, off, 32);
  if (j == 0) {
    float prob = 1.f / (1.f + expf(-(pp + b_ne2[0])));
    ws[OFF_PROB + b * NN + n] = prob;
    ws[OFF_LOGP + b * NN + n] = logf(prob);
    ((int*)(ws + OFF_INV))[b * FLAT + pos] = n;
  }
  float a1 = g_p1[j] / sqrtf(1.f + EPSBN);
  ws[OFF_XI1 + (size_t)(b * NN + n) * 32 + j] = z1 * a1;
}

// ---------------- K2: categorical draw k for sample b; emit tf, ne_k, m1
__global__ __launch_bounds__(256) void k2_sample(
    const int* __restrict__ midx,
    const float* __restrict__ w_p1, const float* __restrict__ b_p1,
    const float* __restrict__ g_p1, const float* __restrict__ be_p1,
    float* __restrict__ ws) {
  int b = blockIdx.x >> 8, k = blockIdx.x & 255;
  int tid = threadIdx.x;
  uint32_t kb0, kb1;
  jax_key(b, kb0, kb1);
  const float* logp = ws + OFF_LOGP + b * NN;
  const float NEGINF = -__builtin_inff();
  float bv = NEGINF; int bn = NN;
#pragma unroll 1
  for (int r = 0; r < 8; ++r) {
    int n = r * 256 + tid;
    uint32_t bits = jax_bits(kb0, kb1, (uint32_t)(k * NN + n));
    float f = __uint_as_float(0x3f800000u | (bits >> 9)) - 1.0f;
    float u = fmaxf(TINYF, f + TINYF);
    float gmb = -logf(-logf(u));
    float v = logp[n] + gmb;
    if (v > bv || (v == bv && n < bn)) { bv = v; bn = n; }
  }
  __shared__ float sv[256];
  __shared__ int   sn[256];
  __shared__ float mpe[CC];
  sv[tid] = bv; sn[tid] = bn;
  __syncthreads();
  for (int s = 128; s > 0; s >>= 1) {
    if (tid < s) {
      float v2 = sv[tid + s]; int n2 = sn[tid + s];
      if (v2 > sv[tid] || (v2 == sv[tid] && n2 < sn[tid])) { sv[tid] = v2; sn[tid] = n2; }
    }
    __syncthreads();
  }
  int best = sn[0];
  if (tid == 0)
    ws[OFF_NEK + b * KK + k] = ws[OFF_PROB + b * NN + best];
  if (tid < CC) {
    int c = tid;
    ws[OFF_TF + (size_t)(b * KK + k) * CC + c] =
        ws[OFF_XI + (size_t)(b * NN + best) * CC + c];
    int pos = midx[b * NN + best];
    int jj = c >> 1;
    float ang = (float)pos * expf((float)(2 * jj) * PE_SCALE);
    mpe[c] = (c & 1) ? cosf(ang) : sinf(ang);
  }
  __syncthreads();
  if (tid < 32) {
    int jj = tid;
    float acc = b_p1[jj];
#pragma unroll
    for (int c = 0; c < CC; ++c) acc += mpe[c] * w_p1[c * 32 + jj];
    float a = g_p1[jj] / sqrtf(1.f + EPSBN);
    ws[OFF_M1 + (size_t)(b * KK + k) * 32 + jj] = acc * a + be_p1[jj];
  }
}

// ---------------- K3: heavy N x K pairwise MLP, GEMM-tiled
// Thread tile: 8 k x 4 q -> z[8][4] (32 regs). m1 transposed in LDS
// [j][k] pad 264. Working set ~75 VGPR: fits any allocation, no spill.
// (History: (256,4)->64 VGPR spilled 1.27GB; (256,2)->128 VGPR spilled
// 0.62GB. Fix = smaller working set, not allocator arm-wrestling.)
__global__ __launch_bounds__(256) void k3_pair(
    const float* __restrict__ w_p2, const float* __restrict__ b_p2,
    const float* __restrict__ g_p2, const float* __restrict__ be_p2,
    const float* __restrict__ w_p3, const float* __restrict__ b_p3,
    float* __restrict__ ws) {
  __shared__ __align__(16) float w2s[1024];       // 4 KB, scaled W2
  __shared__ __align__(16) float m1t[32 * 264];   // 33.8 KB, m1^T [j][k] pad 264
  __shared__ __align__(16) float PQT[8][256];     // 8 KB, planes (n*2+{0,1})
  __shared__ __align__(16) float xi1s[4][32];
  __shared__ __align__(16) float c2f[32];
  __shared__ __align__(16) float w3l[32];
  __shared__ __align__(16) float xIl[4 * 68], xEl[4 * 68];
  __shared__ float sI[4], sE[4];
  int tid = threadIdx.x;
  int b = blockIdx.x >> 9;                        // grid = BS*NN/4 = 1024
  int n0 = (blockIdx.x & 511) * 4;
  int kg = tid >> 3, qg = tid & 7;
  int k0 = kg * 8, q0 = qg * 4;
  // --- prologue: m1 transpose into LDS (thread = k = tid) ---
  {
    const float4* m4 = (const float4*)(ws + OFF_M1 + (size_t)(b * KK + tid) * 32);
#pragma unroll
    for (int q = 0; q < 8; ++q) {
      float4 v = m4[q];
      m1t[(q * 4 + 0) * 264 + tid] = v.x;
      m1t[(q * 4 + 1) * 264 + tid] = v.y;
      m1t[(q * 4 + 2) * 264 + tid] = v.z;
      m1t[(q * 4 + 3) * 264 + tid] = v.w;
    }
  }
  for (int e = tid; e < 1024; e += 256) {
    int jj = e & 31;
    w2s[e] = w_p2[e] * (g_p2[jj] / sqrtf(1.f + EPSBN));
  }
  if (tid < 32) {
    c2f[tid] = b_p2[tid] * (g_p2[tid] / sqrtf(1.f + EPSBN)) + be_p2[tid];
    w3l[tid] = w_p3[tid];
  }
  if (tid < 128) {
    int nn = tid >> 5, jx = tid & 31;
    xi1s[nn][jx] = ws[OFF_XI1 + (size_t)(b * NN + n0 + nn) * 32 + jx];
  }
  float nekv = ws[OFF_NEK + b * KK + tid];
  float b3 = b_p3[0];
  __syncthreads();
  // --- phase b: z[8k][4q] per thread; LDS per jj = 3x b128 only ---
  const float4* w2s4 = (const float4*)w2s;
  const float4 cv = *(const float4*)&c2f[q0];
  const float4 w3v = *(const float4*)&w3l[q0];
#pragma unroll 1
  for (int nn = 0; nn < 4; ++nn) {
    float z[8][4];
#pragma unroll
    for (int i = 0; i < 8; ++i) {
      z[i][0] = cv.x; z[i][1] = cv.y; z[i][2] = cv.z; z[i][3] = cv.w;
    }
#pragma unroll 8
    for (int jj = 0; jj < 32; ++jj) {
      float xv = xi1s[nn][jj];
      float4 w = w2s4[jj * 8 + qg];
      const float4* mr = (const float4*)&m1t[jj * 264 + k0];
      float4 ma = mr[0], mb = mr[1];
      float h[8];
      h[0] = fmaxf(0.f, xv + ma.x); h[1] = fmaxf(0.f, xv + ma.y);
      h[2] = fmaxf(0.f, xv + ma.z); h[3] = fmaxf(0.f, xv + ma.w);
      h[4] = fmaxf(0.f, xv + mb.x); h[5] = fmaxf(0.f, xv + mb.y);
      h[6] = fmaxf(0.f, xv + mb.z); h[7] = fmaxf(0.f, xv + mb.w);
#pragma unroll
      for (int i = 0; i < 8; ++i) {
        z[i][0] += h[i] * w.x; z[i][1] += h[i] * w.y;
        z[i][2] += h[i] * w.z; z[i][3] += h[i] * w.w;
      }
    }
    // epilogue: per-thread partial w3-dot, butterfly across the 8 qg lanes
    float s[8];
#pragma unroll
    for (int i = 0; i < 8; ++i)
      s[i] = fmaxf(0.f, z[i][0]) * w3v.x + fmaxf(0.f, z[i][1]) * w3v.y
           + fmaxf(0.f, z[i][2]) * w3v.z + fmaxf(0.f, z[i][3]) * w3v.w;
#pragma unroll
    for (int i = 0; i < 8; ++i) {
      s[i] += __shfl_xor(s[i], 1, 64);
      s[i] += __shfl_xor(s[i], 2, 64);
      s[i] += __shfl_xor(s[i], 4, 64);
    }
    // lane qg owns k = k0 + qg = tid; ternary chain (NOT s[qg]: rule #20)
    float sv = qg < 4 ? (qg < 2 ? (qg == 0 ? s[0] : s[1]) : (qg == 2 ? s[2] : s[3]))
                      : (qg < 6 ? (qg == 4 ? s[4] : s[5]) : (qg == 6 ? s[6] : s[7]));
    float P = 1.f / (1.f + expf(-(sv + b3)));
    PQT[nn * 2 + 0][tid] = P * nekv;
    PQT[nn * 2 + 1][tid] = (1.f - P) * nekv;
  }
  __syncthreads();
  // --- phase b2: per-n sums of Pi/Pe over k ---
  if (tid < 128) {
    int nn = tid >> 5, jx = tid & 31;
    int pi = nn * 2;
    float s1 = 0.f, s2 = 0.f;
#pragma unroll
    for (int t = 0; t < 8; ++t) {
      s1 += PQT[pi][jx + 32 * t];
      s2 += PQT[pi + 1][jx + 32 * t];
    }
    for (int off = 16; off > 0; off >>= 1) {
      s1 += __shfl_down(s1, off, 32);
      s2 += __shfl_down(s2, off, 32);
    }
    if (jx == 0) { sI[nn] = s1; sE[nn] = s2; }
  }
  __syncthreads();
  // --- phase c: x_intra/x_inter, all 256 threads = (n, c) ---
  {
    int c = tid & 63, n = tid >> 6;
    int pip = n * 2;
    const float4* PI4 = (const float4*)PQT[pip];
    const float4* PE4 = (const float4*)PQT[pip + 1];
    const float* tfg = ws + OFF_TF + (size_t)b * KK * CC + c;
    float aI = 0.f, aE = 0.f;
#pragma unroll 4
    for (int kq = 0; kq < 64; ++kq) {
      float4 piv = PI4[kq], pev = PE4[kq];
      float t0 = tfg[(4 * kq + 0) * 64];
      float t1 = tfg[(4 * kq + 1) * 64];
      float t2 = tfg[(4 * kq + 2) * 64];
      float t3 = tfg[(4 * kq + 3) * 64];
      aI += piv.x * t0 + piv.y * t1 + piv.z * t2 + piv.w * t3;
      aE += pev.x * t0 + pev.y * t1 + pev.z * t2 + pev.w * t3;
    }
    xIl[n * 68 + c] = aI / sI[n];
    xEl[n * 68 + c] = aE / sE[n];
  }
  __syncthreads();
  // --- phase d: delta = xI @ WF[64:128] + xE @ WF[128:192] ---
  {
    int co = tid & 63, nn = tid >> 6;
    const float4* xI4 = (const float4*)&xIl[nn * 68];
    const float4* xE4 = (const float4*)&xEl[nn * 68];
    const float* wI = ws + OFF_WF + 64 * CC + co;
    const float* wE = ws + OFF_WF + 128 * CC + co;
    float dsum = 0.f;
#pragma unroll 4
    for (int cq = 0; cq < 16; ++cq) {
      float4 xi4 = xI4[cq], xe4 = xE4[cq];
      dsum += xi4.x * wI[(4 * cq + 0) * 64] + xi4.y * wI[(4 * cq + 1) * 64]
            + xi4.z * wI[(4 * cq + 2) * 64] + xi4.w * wI[(4 * cq + 3) * 64];
      dsum += xe4.x * wE[(4 * cq + 0) * 64] + xe4.y * wE[(4 * cq + 1) * 64]
            + xe4.z * wE[(4 * cq + 2) * 64] + xe4.w * wE[(4 * cq + 3) * 64];
    }
    ws[OFF_DELTA + (size_t)(b * NN + n0 + nn) * CC + co] = dsum;
  }
}

// ---------------- K4: base resize + masked delta add, coalesced single store
__global__ __launch_bounds__(256) void k4_out(
    const float* __restrict__ input, float* __restrict__ out,
    const float* __restrict__ ws) {
  __shared__ __align__(16) float wfa[64 * 64];
  __shared__ float bfl[64];
  int tid = threadIdx.x;
  const float* wf = ws + OFF_WF;
  for (int e = tid; e < 4096; e += 256) {
    int c = e >> 6, co = e & 63;
    wfa[e] = wf[c * 64 + co] + wf[(192 + c) * 64 + co];
  }
  if (tid < 64) bfl[tid] = ws[OFF_BF + tid];
  __syncthreads();
  int q = tid >> 6, lane = tid & 63;
  int pg = blockIdx.x * 64 + lane;             // grid = BS*FLAT/64 = 512
  int b = pg >> 14, pos = pg & (FLAT - 1);
  const int* inv = (const int*)(ws + OFF_INV);
  float acc[16];
#pragma unroll
  for (int u = 0; u < 16; ++u) acc[u] = bfl[q * 16 + u];
#pragma unroll 4
  for (int c = 0; c < 64; ++c) {
    float xv = input[((size_t)(b * CC + c)) * FLAT + pos];
    const float4* wr = (const float4*)&wfa[c * 64 + q * 16];
#pragma unroll
    for (int u4 = 0; u4 < 4; ++u4) {
      float4 w = wr[u4];
      acc[u4 * 4 + 0] += xv * w.x; acc[u4 * 4 + 1] += xv * w.y;
      acc[u4 * 4 + 2] += xv * w.z; acc[u4 * 4 + 3] += xv * w.w;
    }
  }
  int n = inv[pg];
  if (n >= 0) {
    const float4* dr = (const float4*)(ws + OFF_DELTA + (size_t)(b * NN + n) * CC + q * 16);
#pragma unroll
    for (int u4 = 0; u4 < 4; ++u4) {
      float4 dv = dr[u4];
      acc[u4 * 4 + 0] += dv.x; acc[u4 * 4 + 1] += dv.y;
      acc[u4 * 4 + 2] += dv.z; acc[u4 * 4 + 3] += dv.w;
    }
  }
#pragma unroll
  for (int u = 0; u < 16; ++u)
    out[((size_t)(b * CC + q * 16 + u)) * FLAT + pos] = acc[u];
}

// ---------------- launch ----------------
extern "C" void kernel_launch(void* const* d_in, const int* in_sizes, int n_in,
                              void* d_out, int out_size, void* d_ws, size_t ws_size,
                              hipStream_t stream) {
  const float* input = (const float*)d_in[0];
  const int*   midx  = (const int*)  d_in[1];
  const float* w_ne1 = (const float*)d_in[2];
  const float* b_ne1 = (const float*)d_in[3];
  const float* g_ne  = (const float*)d_in[4];
  const float* be_ne = (const float*)d_in[5];
  const float* w_ne2 = (const float*)d_in[6];
  const float* b_ne2 = (const float*)d_in[7];
  const float* w_p1  = (const float*)d_in[8];
  const float* b_p1  = (const float*)d_in[9];
  const float* g_p1  = (const float*)d_in[10];
  const float* be_p1 = (const float*)d_in[11];
  const float* w_p2  = (const float*)d_in[12];
  const float* b_p2  = (const float*)d_in[13];
  const float* g_p2  = (const float*)d_in[14];
  const float* be_p2 = (const float*)d_in[15];
  const float* w_p3  = (const float*)d_in[16];
  const float* b_p3  = (const float*)d_in[17];
  const float* w_r1  = (const float*)d_in[18];
  const float* b_r1  = (const float*)d_in[19];
  const float* w_r2  = (const float*)d_in[20];
  const float* b_r2  = (const float*)d_in[21];
  float* out = (float*)d_out;
  float* ws  = (float*)d_ws;

  k0_fold<<<dim3(256), dim3(64), 0, stream>>>(w_r1, b_r1, w_r2, b_r2, ws);
  k1_xi<<<dim3(BS * NN / 8), dim3(256), 0, stream>>>(
      input, midx, w_ne1, b_ne1, g_ne, be_ne, w_ne2, b_ne2, w_p1, g_p1, ws);
  k2_sample<<<dim3(BS * KK), dim3(256), 0, stream>>>(
      midx, w_p1, b_p1, g_p1, be_p1, ws);
  k3_pair<<<dim3(BS * NN / 4), dim3(256), 0, stream>>>(
      w_p2, b_p2, g_p2, be_p2, w_p3, b_p3, ws);
  k4_out<<<dim3(BS * FLAT / 64), dim3(256), 0, stream>>>(input, out, ws);
}

// Round 11
// 190.932 us; speedup vs baseline: 2.8752x; 1.0064x over previous
//
#include <hip/hip_runtime.h>
#include <cstdint>
#include <cmath>

// ---------------- problem constants ----------------
#define BS    2
#define CC    64
#define FLAT  16384
#define NN    2048
#define KK    256
#define EPSBN 1e-5f
#define TINYF 1.17549435e-38f
#define PE_SCALE -0.14391156831212787f
#define JAX_PARTITIONABLE 1

// ---------------- workspace layout (float offsets) ----------------
#define OFF_XI    0                          // [BS][NN][CC]
#define OFF_XI1   (OFF_XI   + BS*NN*CC)      // [BS][NN][32]
#define OFF_PROB  (OFF_XI1  + BS*NN*32)      // [BS][NN]
#define OFF_LOGP  (OFF_PROB + BS*NN)         // [BS][NN]
#define OFF_NEK   (OFF_LOGP + BS*NN)         // [BS][KK]
#define OFF_TF    (OFF_NEK  + BS*KK)         // [BS][KK][CC]
#define OFF_M1    (OFF_TF   + BS*KK*CC)      // [BS][KK][32]
#define OFF_DELTA (OFF_M1   + BS*KK*32)      // [BS][NN][CC]
#define OFF_WF    (OFF_DELTA+ BS*NN*CC)      // [256][64]
#define OFF_BF    (OFF_WF   + 256*CC)        // [64]
#define OFF_INV   (OFF_BF   + CC)            // [BS][FLAT] ints
#define OFF_PP    (OFF_INV  + BS*FLAT)       // [BS][NN][KK] Pi plane (Pe = nek - Pi)
// total ~1.81M floats ~= 7.3 MB

// ---------------- threefry2x32 ----------------
__device__ __forceinline__ uint32_t rotl32(uint32_t x, int r) {
  return (x << r) | (x >> (32 - r));
}
__device__ __forceinline__ void tf2x32(uint32_t k0, uint32_t k1,
                                       uint32_t& x0, uint32_t& x1) {
  uint32_t k2 = k0 ^ k1 ^ 0x1BD11BDAu;
  x0 += k0; x1 += k1;
#define TFR(r) { x0 += x1; x1 = rotl32(x1, r); x1 ^= x0; }
  TFR(13) TFR(15) TFR(26) TFR(6)  x0 += k1; x1 += k2 + 1u;
  TFR(17) TFR(29) TFR(16) TFR(24) x0 += k2; x1 += k0 + 2u;
  TFR(13) TFR(15) TFR(26) TFR(6)  x0 += k0; x1 += k1 + 3u;
  TFR(17) TFR(29) TFR(16) TFR(24) x0 += k1; x1 += k2 + 4u;
  TFR(13) TFR(15) TFR(26) TFR(6)  x0 += k2; x1 += k0 + 5u;
#undef TFR
}
__device__ __forceinline__ void jax_key(int b, uint32_t& k0, uint32_t& k1) {
#if JAX_PARTITIONABLE
  uint32_t x0 = 0u, x1 = (uint32_t)b;
  tf2x32(0u, 42u, x0, x1);
  k0 = x0; k1 = x1;
#else
  uint32_t a0 = 0u, a1 = 2u, c0 = 1u, c1 = 3u;
  tf2x32(0u, 42u, a0, a1);
  tf2x32(0u, 42u, c0, c1);
  if (b == 0) { k0 = a0; k1 = c0; } else { k0 = a1; k1 = c1; }
#endif
}
__device__ __forceinline__ uint32_t jax_bits(uint32_t k0, uint32_t k1, uint32_t i) {
#if JAX_PARTITIONABLE
  uint32_t x0 = 0u, x1 = i;
  tf2x32(k0, k1, x0, x1);
  return x0 ^ x1;
#else
  const uint32_t half = (uint32_t)(KK * NN) / 2u;
  uint32_t x0, x1;
  if (i < half) { x0 = i; x1 = i + half; tf2x32(k0, k1, x0, x1); return x0; }
  else          { x0 = i - half; x1 = i; tf2x32(k0, k1, x0, x1); return x1; }
#endif
}

// ---------------- K0: fold resize weights + init inverse mask map
__global__ void k0_fold(const float* __restrict__ w_r1, const float* __restrict__ b_r1,
                        const float* __restrict__ w_r2, const float* __restrict__ b_r2,
                        float* __restrict__ ws) {
  int c = blockIdx.x;      // 0..255
  int co = threadIdx.x;    // 0..63
  float acc = 0.f;
  for (int f = 0; f < 128; ++f)
    acc += w_r1[c * 128 + f] * w_r2[f * 64 + co];
  ws[OFF_WF + c * 64 + co] = acc;
  if (blockIdx.x == 0) {
    float bb = b_r2[co];
    for (int f = 0; f < 128; ++f) bb += b_r1[f] * w_r2[f * 64 + co];
    ws[OFF_BF + co] = bb;
  }
  int* inv = (int*)(ws + OFF_INV);
  int t = blockIdx.x * 64 + threadIdx.x;       // 0..16383
  inv[t] = -1;
  inv[t + BS * FLAT / 2] = -1;
}

// ---------------- K1: 32 threads per n: xi, prob/logp, xi1, inv map
__global__ __launch_bounds__(256) void k1_xi(
    const float* __restrict__ input, const int* __restrict__ midx,
    const float* __restrict__ w_ne1, const float* __restrict__ b_ne1,
    const float* __restrict__ g_ne,  const float* __restrict__ be_ne,
    const float* __restrict__ w_ne2, const float* __restrict__ b_ne2,
    const float* __restrict__ w_p1,  const float* __restrict__ g_p1,
    float* __restrict__ ws) {
  int tid = threadIdx.x;
  int j = tid & 31, nl = tid >> 5;             // 8 n per block
  int bn = blockIdx.x * 8 + nl;                // grid = BS*NN/8 = 512
  int b = bn >> 11, n = bn & (NN - 1);
  int pos = midx[b * NN + n];
  __shared__ float xis[8][66];
  float d = expf((float)(2 * j) * PE_SCALE);
  float ang = (float)pos * d;
  float xs = sinf(ang) + input[((size_t)(b * CC + 2 * j)) * FLAT + pos];
  float xc = cosf(ang) + input[((size_t)(b * CC + 2 * j + 1)) * FLAT + pos];
  xis[nl][2 * j] = xs; xis[nl][2 * j + 1] = xc;
  float2 v2; v2.x = xs; v2.y = xc;
  ((float2*)(ws + OFF_XI + (size_t)(b * NN + n) * CC))[j] = v2;
  __syncthreads();
  float zne = b_ne1[j];
  float z1 = 0.f;
#pragma unroll
  for (int c2 = 0; c2 < CC; ++c2) {
    float xv = xis[nl][c2];
    zne += xv * w_ne1[c2 * 32 + j];
    z1  += xv * w_p1[c2 * 32 + j];
  }
  float ane = g_ne[j] / sqrtf(1.f + EPSBN);
  float h = fmaxf(0.f, zne * ane + be_ne[j]);
  float pp = h * w_ne2[j];
  for (int off = 16; off > 0; off >>= 1) pp += __shfl_down(pp, off, 32);
  if (j == 0) {
    float prob = 1.f / (1.f + expf(-(pp + b_ne2[0])));
    ws[OFF_PROB + b * NN + n] = prob;
    ws[OFF_LOGP + b * NN + n] = logf(prob);
    ((int*)(ws + OFF_INV))[b * FLAT + pos] = n;
  }
  float a1 = g_p1[j] / sqrtf(1.f + EPSBN);
  ws[OFF_XI1 + (size_t)(b * NN + n) * 32 + j] = z1 * a1;
}

// ---------------- K2: categorical draw k for sample b; emit tf, ne_k, m1
__global__ __launch_bounds__(256) void k2_sample(
    const int* __restrict__ midx,
    const float* __restrict__ w_p1, const float* __restrict__ b_p1,
    const float* __restrict__ g_p1, const float* __restrict__ be_p1,
    float* __restrict__ ws) {
  int b = blockIdx.x >> 8, k = blockIdx.x & 255;
  int tid = threadIdx.x;
  uint32_t kb0, kb1;
  jax_key(b, kb0, kb1);
  const float* logp = ws + OFF_LOGP + b * NN;
  const float NEGINF = -__builtin_inff();
  float bv = NEGINF; int bn = NN;
#pragma unroll 1
  for (int r = 0; r < 8; ++r) {
    int n = r * 256 + tid;
    uint32_t bits = jax_bits(kb0, kb1, (uint32_t)(k * NN + n));
    float f = __uint_as_float(0x3f800000u | (bits >> 9)) - 1.0f;
    float u = fmaxf(TINYF, f + TINYF);
    float gmb = -logf(-logf(u));
    float v = logp[n] + gmb;
    if (v > bv || (v == bv && n < bn)) { bv = v; bn = n; }
  }
  __shared__ float sv[256];
  __shared__ int   sn[256];
  __shared__ float mpe[CC];
  sv[tid] = bv; sn[tid] = bn;
  __syncthreads();
  for (int s = 128; s > 0; s >>= 1) {
    if (tid < s) {
      float v2 = sv[tid + s]; int n2 = sn[tid + s];
      if (v2 > sv[tid] || (v2 == sv[tid] && n2 < sn[tid])) { sv[tid] = v2; sn[tid] = n2; }
    }
    __syncthreads();
  }
  int best = sn[0];
  if (tid == 0)
    ws[OFF_NEK + b * KK + k] = ws[OFF_PROB + b * NN + best];
  if (tid < CC) {
    int c = tid;
    ws[OFF_TF + (size_t)(b * KK + k) * CC + c] =
        ws[OFF_XI + (size_t)(b * NN + best) * CC + c];
    int pos = midx[b * NN + best];
    int jj = c >> 1;
    float ang = (float)pos * expf((float)(2 * jj) * PE_SCALE);
    mpe[c] = (c & 1) ? cosf(ang) : sinf(ang);
  }
  __syncthreads();
  if (tid < 32) {
    int jj = tid;
    float acc = b_p1[jj];
#pragma unroll
    for (int c = 0; c < CC; ++c) acc += mpe[c] * w_p1[c * 32 + jj];
    float a = g_p1[jj] / sqrtf(1.f + EPSBN);
    ws[OFF_M1 + (size_t)(b * KK + k) * 32 + jj] = acc * a + be_p1[jj];
  }
}

// ---------------- K3a: phase b only — P-plane GEMM, h precomputed in LDS
// LDS 38.7 KB -> 4 blocks/CU (was 48 KB -> 3). m1 row in 32 regs (loaded
// once); per nn: h[j][k] staged once (kills the 8x duplicated h-ops of
// round 8), GEMM loop = 2xb128 h + 1xb128 w2 + 32 FMA per jj.
__global__ __launch_bounds__(256) void k3a_pairP(
    const float* __restrict__ w_p2, const float* __restrict__ b_p2,
    const float* __restrict__ g_p2, const float* __restrict__ be_p2,
    const float* __restrict__ w_p3, const float* __restrict__ b_p3,
    float* __restrict__ ws) {
  __shared__ __align__(16) float w2s[1024];       // 4 KB, scaled W2
  __shared__ __align__(16) float hbuf[32 * 264];  // 33.8 KB, h[j][k] pad 264
  __shared__ __align__(16) float xi1s[4][32];
  __shared__ __align__(16) float c2f[32];
  __shared__ __align__(16) float w3l[32];
  int tid = threadIdx.x;
  int b = blockIdx.x >> 9;                        // grid = BS*NN/4 = 1024
  int n0 = (blockIdx.x & 511) * 4;
  int kg = tid >> 3, qg = tid & 7;
  int k0 = kg * 8, q0 = qg * 4;
  // --- prologue: m1 row (k = tid) into registers, once ---
  float m1r[32];
  {
    const float4* m4 = (const float4*)(ws + OFF_M1 + (size_t)(b * KK + tid) * 32);
#pragma unroll
    for (int q = 0; q < 8; ++q) {
      float4 v = m4[q];
      m1r[q * 4 + 0] = v.x; m1r[q * 4 + 1] = v.y;
      m1r[q * 4 + 2] = v.z; m1r[q * 4 + 3] = v.w;
    }
  }
  for (int e = tid; e < 1024; e += 256) {
    int jj = e & 31;
    w2s[e] = w_p2[e] * (g_p2[jj] / sqrtf(1.f + EPSBN));
  }
  if (tid < 32) {
    c2f[tid] = b_p2[tid] * (g_p2[tid] / sqrtf(1.f + EPSBN)) + be_p2[tid];
    w3l[tid] = w_p3[tid];
  }
  if (tid < 128) {
    int nn = tid >> 5, jx = tid & 31;
    xi1s[nn][jx] = ws[OFF_XI1 + (size_t)(b * NN + n0 + nn) * 32 + jx];
  }
  float nekv = ws[OFF_NEK + b * KK + tid];
  float b3 = b_p3[0];
  __syncthreads();
  const float4* w2s4 = (const float4*)w2s;
  const float4 cv = *(const float4*)&c2f[q0];
  const float4 w3v = *(const float4*)&w3l[q0];
#pragma unroll 1
  for (int nn = 0; nn < 4; ++nn) {
    // stage h[j][k=tid]: consecutive-lane writes, conflict-free
#pragma unroll
    for (int j = 0; j < 32; ++j)
      hbuf[j * 264 + tid] = fmaxf(0.f, xi1s[nn][j] + m1r[j]);
    __syncthreads();
    float z[8][4];
#pragma unroll
    for (int i = 0; i < 8; ++i) {
      z[i][0] = cv.x; z[i][1] = cv.y; z[i][2] = cv.z; z[i][3] = cv.w;
    }
#pragma unroll 8
    for (int jj = 0; jj < 32; ++jj) {
      float4 w = w2s4[jj * 8 + qg];
      const float4* mr = (const float4*)&hbuf[jj * 264 + k0];
      float4 ha = mr[0], hb = mr[1];
      z[0][0] += ha.x * w.x; z[0][1] += ha.x * w.y; z[0][2] += ha.x * w.z; z[0][3] += ha.x * w.w;
      z[1][0] += ha.y * w.x; z[1][1] += ha.y * w.y; z[1][2] += ha.y * w.z; z[1][3] += ha.y * w.w;
      z[2][0] += ha.z * w.x; z[2][1] += ha.z * w.y; z[2][2] += ha.z * w.z; z[2][3] += ha.z * w.w;
      z[3][0] += ha.w * w.x; z[3][1] += ha.w * w.y; z[3][2] += ha.w * w.z; z[3][3] += ha.w * w.w;
      z[4][0] += hb.x * w.x; z[4][1] += hb.x * w.y; z[4][2] += hb.x * w.z; z[4][3] += hb.x * w.w;
      z[5][0] += hb.y * w.x; z[5][1] += hb.y * w.y; z[5][2] += hb.y * w.z; z[5][3] += hb.y * w.w;
      z[6][0] += hb.z * w.x; z[6][1] += hb.z * w.y; z[6][2] += hb.z * w.z; z[6][3] += hb.z * w.w;
      z[7][0] += hb.w * w.x; z[7][1] += hb.w * w.y; z[7][2] += hb.w * w.z; z[7][3] += hb.w * w.w;
    }
    // epilogue: per-thread partial w3-dot, butterfly across the 8 qg lanes
    float s[8];
#pragma unroll
    for (int i = 0; i < 8; ++i)
      s[i] = fmaxf(0.f, z[i][0]) * w3v.x + fmaxf(0.f, z[i][1]) * w3v.y
           + fmaxf(0.f, z[i][2]) * w3v.z + fmaxf(0.f, z[i][3]) * w3v.w;
#pragma unroll
    for (int i = 0; i < 8; ++i) {
      s[i] += __shfl_xor(s[i], 1, 64);
      s[i] += __shfl_xor(s[i], 2, 64);
      s[i] += __shfl_xor(s[i], 4, 64);
    }
    // lane qg owns k = k0 + qg = tid; ternary chain (NOT s[qg]: rule #20)
    float sv = qg < 4 ? (qg < 2 ? (qg == 0 ? s[0] : s[1]) : (qg == 2 ? s[2] : s[3]))
                      : (qg < 6 ? (qg == 4 ? s[4] : s[5]) : (qg == 6 ? s[6] : s[7]));
    float P = 1.f / (1.f + expf(-(sv + b3)));
    ws[OFF_PP + (size_t)(b * NN + n0 + nn) * KK + tid] = P * nekv;
    __syncthreads();                              // hbuf reused next nn
  }
}

// ---------------- K3b: sums + x_intra/x_inter + delta (high occupancy)
__global__ __launch_bounds__(256) void k3b_ctx(
    float* __restrict__ ws) {
  __shared__ __align__(16) float Pis[4][256];     // 4 KB
  __shared__ __align__(16) float nekl[256];
  __shared__ __align__(16) float xIl[4 * 68], xEl[4 * 68];
  __shared__ float sI[4], sE[4];
  int tid = threadIdx.x;
  int b = blockIdx.x >> 9;                        // grid = BS*NN/4 = 1024
  int n0 = (blockIdx.x & 511) * 4;
#pragma unroll
  for (int e = 0; e < 4; ++e)
    Pis[e][tid] = ws[OFF_PP + (size_t)(b * NN + n0 + e) * KK + tid];
  nekl[tid] = ws[OFF_NEK + b * KK + tid];
  __syncthreads();
  // sums over k (Pe = nek - Pi)
  if (tid < 128) {
    int nn = tid >> 5, jx = tid & 31;
    float s1 = 0.f, s2 = 0.f;
#pragma unroll
    for (int t = 0; t < 8; ++t) {
      float pi = Pis[nn][jx + 32 * t];
      s1 += pi;
      s2 += nekl[jx + 32 * t] - pi;
    }
    for (int off = 16; off > 0; off >>= 1) {
      s1 += __shfl_down(s1, off, 32);
      s2 += __shfl_down(s2, off, 32);
    }
    if (jx == 0) { sI[nn] = s1; sE[nn] = s2; }
  }
  __syncthreads();
  // x_intra/x_inter: thread = (n, c)
  {
    int c = tid & 63, n = tid >> 6;
    const float4* PI4 = (const float4*)Pis[n];
    const float4* NE4 = (const float4*)nekl;
    const float* tfg = ws + OFF_TF + (size_t)b * KK * CC + c;
    float aI = 0.f, aE = 0.f;
#pragma unroll 4
    for (int kq = 0; kq < 64; ++kq) {
      float4 piv = PI4[kq], nev = NE4[kq];
      float t0 = tfg[(4 * kq + 0) * 64];
      float t1 = tfg[(4 * kq + 1) * 64];
      float t2 = tfg[(4 * kq + 2) * 64];
      float t3 = tfg[(4 * kq + 3) * 64];
      aI += piv.x * t0 + piv.y * t1 + piv.z * t2 + piv.w * t3;
      aE += (nev.x - piv.x) * t0 + (nev.y - piv.y) * t1
          + (nev.z - piv.z) * t2 + (nev.w - piv.w) * t3;
    }
    xIl[n * 68 + c] = aI / sI[n];
    xEl[n * 68 + c] = aE / sE[n];
  }
  __syncthreads();
  // delta = xI @ WF[64:128] + xE @ WF[128:192]
  {
    int co = tid & 63, nn = tid >> 6;
    const float4* xI4 = (const float4*)&xIl[nn * 68];
    const float4* xE4 = (const float4*)&xEl[nn * 68];
    const float* wI = ws + OFF_WF + 64 * CC + co;
    const float* wE = ws + OFF_WF + 128 * CC + co;
    float dsum = 0.f;
#pragma unroll 4
    for (int cq = 0; cq < 16; ++cq) {
      float4 xi4 = xI4[cq], xe4 = xE4[cq];
      dsum += xi4.x * wI[(4 * cq + 0) * 64] + xi4.y * wI[(4 * cq + 1) * 64]
            + xi4.z * wI[(4 * cq + 2) * 64] + xi4.w * wI[(4 * cq + 3) * 64];
      dsum += xe4.x * wE[(4 * cq + 0) * 64] + xe4.y * wE[(4 * cq + 1) * 64]
            + xe4.z * wE[(4 * cq + 2) * 64] + xe4.w * wE[(4 * cq + 3) * 64];
    }
    ws[OFF_DELTA + (size_t)(b * NN + n0 + nn) * CC + co] = dsum;
  }
}

// ---------------- K4: base resize + masked delta add, coalesced single store
__global__ __launch_bounds__(256) void k4_out(
    const float* __restrict__ input, float* __restrict__ out,
    const float* __restrict__ ws) {
  __shared__ __align__(16) float wfa[64 * 64];
  __shared__ float bfl[64];
  int tid = threadIdx.x;
  const float* wf = ws + OFF_WF;
  for (int e = tid; e < 4096; e += 256) {
    int c = e >> 6, co = e & 63;
    wfa[e] = wf[c * 64 + co] + wf[(192 + c) * 64 + co];
  }
  if (tid < 64) bfl[tid] = ws[OFF_BF + tid];
  __syncthreads();
  int q = tid >> 6, lane = tid & 63;
  int pg = blockIdx.x * 64 + lane;             // grid = BS*FLAT/64 = 512
  int b = pg >> 14, pos = pg & (FLAT - 1);
  const int* inv = (const int*)(ws + OFF_INV);
  float acc[16];
#pragma unroll
  for (int u = 0; u < 16; ++u) acc[u] = bfl[q * 16 + u];
#pragma unroll 4
  for (int c = 0; c < 64; ++c) {
    float xv = input[((size_t)(b * CC + c)) * FLAT + pos];
    const float4* wr = (const float4*)&wfa[c * 64 + q * 16];
#pragma unroll
    for (int u4 = 0; u4 < 4; ++u4) {
      float4 w = wr[u4];
      acc[u4 * 4 + 0] += xv * w.x; acc[u4 * 4 + 1] += xv * w.y;
      acc[u4 * 4 + 2] += xv * w.z; acc[u4 * 4 + 3] += xv * w.w;
    }
  }
  int n = inv[pg];
  if (n >= 0) {
    const float4* dr = (const float4*)(ws + OFF_DELTA + (size_t)(b * NN + n) * CC + q * 16);
#pragma unroll
    for (int u4 = 0; u4 < 4; ++u4) {
      float4 dv = dr[u4];
      acc[u4 * 4 + 0] += dv.x; acc[u4 * 4 + 1] += dv.y;
      acc[u4 * 4 + 2] += dv.z; acc[u4 * 4 + 3] += dv.w;
    }
  }
#pragma unroll
  for (int u = 0; u < 16; ++u)
    out[((size_t)(b * CC + q * 16 + u)) * FLAT + pos] = acc[u];
}

// ---------------- launch ----------------
extern "C" void kernel_launch(void* const* d_in, const int* in_sizes, int n_in,
                              void* d_out, int out_size, void* d_ws, size_t ws_size,
                              hipStream_t stream) {
  const float* input = (const float*)d_in[0];
  const int*   midx  = (const int*)  d_in[1];
  const float* w_ne1 = (const float*)d_in[2];
  const float* b_ne1 = (const float*)d_in[3];
  const float* g_ne  = (const float*)d_in[4];
  const float* be_ne = (const float*)d_in[5];
  const float* w_ne2 = (const float*)d_in[6];
  const float* b_ne2 = (const float*)d_in[7];
  const float* w_p1  = (const float*)d_in[8];
  const float* b_p1  = (const float*)d_in[9];
  const float* g_p1  = (const float*)d_in[10];
  const float* be_p1 = (const float*)d_in[11];
  const float* w_p2  = (const float*)d_in[12];
  const float* b_p2  = (const float*)d_in[13];
  const float* g_p2  = (const float*)d_in[14];
  const float* be_p2 = (const float*)d_in[15];
  const float* w_p3  = (const float*)d_in[16];
  const float* b_p3  = (const float*)d_in[17];
  const float* w_r1  = (const float*)d_in[18];
  const float* b_r1  = (const float*)d_in[19];
  const float* w_r2  = (const float*)d_in[20];
  const float* b_r2  = (const float*)d_in[21];
  float* out = (float*)d_out;
  float* ws  = (float*)d_ws;

  k0_fold<<<dim3(256), dim3(64), 0, stream>>>(w_r1, b_r1, w_r2, b_r2, ws);
  k1_xi<<<dim3(BS * NN / 8), dim3(256), 0, stream>>>(
      input, midx, w_ne1, b_ne1, g_ne, be_ne, w_ne2, b_ne2, w_p1, g_p1, ws);
  k2_sample<<<dim3(BS * KK), dim3(256), 0, stream>>>(
      midx, w_p1, b_p1, g_p1, be_p1, ws);
  k3a_pairP<<<dim3(BS * NN / 4), dim3(256), 0, stream>>>(
      w_p2, b_p2, g_p2, be_p2, w_p3, b_p3, ws);
  k3b_ctx<<<dim3(BS * NN / 4), dim3(256), 0, stream>>>(ws);
  k4_out<<<dim3(BS * FLAT / 64), dim3(256), 0, stream>>>(input, out, ws);
}

// Round 12
// 182.078 us; speedup vs baseline: 3.0150x; 1.0486x over previous
//
#include <hip/hip_runtime.h>
#include <cstdint>
#include <cmath>

// ---------------- problem constants ----------------
#define BS    2
#define CC    64
#define FLAT  16384
#define NN    2048
#define KK    256
#define EPSBN 1e-5f
#define TINYF 1.17549435e-38f
#define PE_SCALE -0.14391156831212787f
#define JAX_PARTITIONABLE 1

// ---------------- workspace layout (float offsets) ----------------
#define OFF_XI    0                          // [BS][NN][CC]
#define OFF_XI1   (OFF_XI   + BS*NN*CC)      // [BS][NN][32]
#define OFF_PROB  (OFF_XI1  + BS*NN*32)      // [BS][NN]
#define OFF_LOGP  (OFF_PROB + BS*NN)         // [BS][NN]
#define OFF_NEK   (OFF_LOGP + BS*NN)         // [BS][KK]
#define OFF_TF    (OFF_NEK  + BS*KK)         // [BS][KK][CC]
#define OFF_M1    (OFF_TF   + BS*KK*CC)      // [BS][KK][32]
#define OFF_DELTA (OFF_M1   + BS*KK*32)      // [BS][NN][CC]
#define OFF_WF    (OFF_DELTA+ BS*NN*CC)      // [256][64]
#define OFF_BF    (OFF_WF   + 256*CC)        // [64]
#define OFF_INV   (OFF_BF   + CC)            // [BS][FLAT] ints

// ---------------- threefry2x32 ----------------
__device__ __forceinline__ uint32_t rotl32(uint32_t x, int r) {
  return (x << r) | (x >> (32 - r));
}
__device__ __forceinline__ void tf2x32(uint32_t k0, uint32_t k1,
                                       uint32_t& x0, uint32_t& x1) {
  uint32_t k2 = k0 ^ k1 ^ 0x1BD11BDAu;
  x0 += k0; x1 += k1;
#define TFR(r) { x0 += x1; x1 = rotl32(x1, r); x1 ^= x0; }
  TFR(13) TFR(15) TFR(26) TFR(6)  x0 += k1; x1 += k2 + 1u;
  TFR(17) TFR(29) TFR(16) TFR(24) x0 += k2; x1 += k0 + 2u;
  TFR(13) TFR(15) TFR(26) TFR(6)  x0 += k0; x1 += k1 + 3u;
  TFR(17) TFR(29) TFR(16) TFR(24) x0 += k1; x1 += k2 + 4u;
  TFR(13) TFR(15) TFR(26) TFR(6)  x0 += k2; x1 += k0 + 5u;
#undef TFR
}
__device__ __forceinline__ void jax_key(int b, uint32_t& k0, uint32_t& k1) {
#if JAX_PARTITIONABLE
  uint32_t x0 = 0u, x1 = (uint32_t)b;
  tf2x32(0u, 42u, x0, x1);
  k0 = x0; k1 = x1;
#else
  uint32_t a0 = 0u, a1 = 2u, c0 = 1u, c1 = 3u;
  tf2x32(0u, 42u, a0, a1);
  tf2x32(0u, 42u, c0, c1);
  if (b == 0) { k0 = a0; k1 = c0; } else { k0 = a1; k1 = c1; }
#endif
}
__device__ __forceinline__ uint32_t jax_bits(uint32_t k0, uint32_t k1, uint32_t i) {
#if JAX_PARTITIONABLE
  uint32_t x0 = 0u, x1 = i;
  tf2x32(k0, k1, x0, x1);
  return x0 ^ x1;
#else
  const uint32_t half = (uint32_t)(KK * NN) / 2u;
  uint32_t x0, x1;
  if (i < half) { x0 = i; x1 = i + half; tf2x32(k0, k1, x0, x1); return x0; }
  else          { x0 = i - half; x1 = i; tf2x32(k0, k1, x0, x1); return x1; }
#endif
}

// ---------------- K0: fold resize weights + init inverse mask map
__global__ void k0_fold(const float* __restrict__ w_r1, const float* __restrict__ b_r1,
                        const float* __restrict__ w_r2, const float* __restrict__ b_r2,
                        float* __restrict__ ws) {
  int c = blockIdx.x;      // 0..255
  int co = threadIdx.x;    // 0..63
  float acc = 0.f;
  for (int f = 0; f < 128; ++f)
    acc += w_r1[c * 128 + f] * w_r2[f * 64 + co];
  ws[OFF_WF + c * 64 + co] = acc;
  if (blockIdx.x == 0) {
    float bb = b_r2[co];
    for (int f = 0; f < 128; ++f) bb += b_r1[f] * w_r2[f * 64 + co];
    ws[OFF_BF + co] = bb;
  }
  int* inv = (int*)(ws + OFF_INV);
  int t = blockIdx.x * 64 + threadIdx.x;       // 0..16383
  inv[t] = -1;
  inv[t + BS * FLAT / 2] = -1;
}

// ---------------- K1: 32 threads per n: xi, prob/logp, xi1, inv map
__global__ __launch_bounds__(256) void k1_xi(
    const float* __restrict__ input, const int* __restrict__ midx,
    const float* __restrict__ w_ne1, const float* __restrict__ b_ne1,
    const float* __restrict__ g_ne,  const float* __restrict__ be_ne,
    const float* __restrict__ w_ne2, const float* __restrict__ b_ne2,
    const float* __restrict__ w_p1,  const float* __restrict__ g_p1,
    float* __restrict__ ws) {
  int tid = threadIdx.x;
  int j = tid & 31, nl = tid >> 5;             // 8 n per block
  int bn = blockIdx.x * 8 + nl;                // grid = BS*NN/8 = 512
  int b = bn >> 11, n = bn & (NN - 1);
  int pos = midx[b * NN + n];
  __shared__ float xis[8][66];
  float d = expf((float)(2 * j) * PE_SCALE);
  float ang = (float)pos * d;
  float xs = sinf(ang) + input[((size_t)(b * CC + 2 * j)) * FLAT + pos];
  float xc = cosf(ang) + input[((size_t)(b * CC + 2 * j + 1)) * FLAT + pos];
  xis[nl][2 * j] = xs; xis[nl][2 * j + 1] = xc;
  float2 v2; v2.x = xs; v2.y = xc;
  ((float2*)(ws + OFF_XI + (size_t)(b * NN + n) * CC))[j] = v2;
  __syncthreads();
  float zne = b_ne1[j];
  float z1 = 0.f;
#pragma unroll
  for (int c2 = 0; c2 < CC; ++c2) {
    float xv = xis[nl][c2];
    zne += xv * w_ne1[c2 * 32 + j];
    z1  += xv * w_p1[c2 * 32 + j];
  }
  float ane = g_ne[j] / sqrtf(1.f + EPSBN);
  float h = fmaxf(0.f, zne * ane + be_ne[j]);
  float pp = h * w_ne2[j];
  for (int off = 16; off > 0; off >>= 1) pp += __shfl_down(pp, off, 32);
  if (j == 0) {
    float prob = 1.f / (1.f + expf(-(pp + b_ne2[0])));
    ws[OFF_PROB + b * NN + n] = prob;
    ws[OFF_LOGP + b * NN + n] = logf(prob);
    ((int*)(ws + OFF_INV))[b * FLAT + pos] = n;
  }
  float a1 = g_p1[j] / sqrtf(1.f + EPSBN);
  ws[OFF_XI1 + (size_t)(b * NN + n) * 32 + j] = z1 * a1;
}

// ---------------- K2: categorical draw k for sample b; emit tf, ne_k, m1
__global__ __launch_bounds__(256) void k2_sample(
    const int* __restrict__ midx,
    const float* __restrict__ w_p1, const float* __restrict__ b_p1,
    const float* __restrict__ g_p1, const float* __restrict__ be_p1,
    float* __restrict__ ws) {
  int b = blockIdx.x >> 8, k = blockIdx.x & 255;
  int tid = threadIdx.x;
  uint32_t kb0, kb1;
  jax_key(b, kb0, kb1);
  const float* logp = ws + OFF_LOGP + b * NN;
  const float NEGINF = -__builtin_inff();
  float bv = NEGINF; int bn = NN;
#pragma unroll 1
  for (int r = 0; r < 8; ++r) {
    int n = r * 256 + tid;
    uint32_t bits = jax_bits(kb0, kb1, (uint32_t)(k * NN + n));
    float f = __uint_as_float(0x3f800000u | (bits >> 9)) - 1.0f;
    float u = fmaxf(TINYF, f + TINYF);
    float gmb = -logf(-logf(u));
    float v = logp[n] + gmb;
    if (v > bv || (v == bv && n < bn)) { bv = v; bn = n; }
  }
  __shared__ float sv[256];
  __shared__ int   sn[256];
  __shared__ float mpe[CC];
  sv[tid] = bv; sn[tid] = bn;
  __syncthreads();
  for (int s = 128; s > 0; s >>= 1) {
    if (tid < s) {
      float v2 = sv[tid + s]; int n2 = sn[tid + s];
      if (v2 > sv[tid] || (v2 == sv[tid] && n2 < sn[tid])) { sv[tid] = v2; sn[tid] = n2; }
    }
    __syncthreads();
  }
  int best = sn[0];
  if (tid == 0)
    ws[OFF_NEK + b * KK + k] = ws[OFF_PROB + b * NN + best];
  if (tid < CC) {
    int c = tid;
    ws[OFF_TF + (size_t)(b * KK + k) * CC + c] =
        ws[OFF_XI + (size_t)(b * NN + best) * CC + c];
    int pos = midx[b * NN + best];
    int jj = c >> 1;
    float ang = (float)pos * expf((float)(2 * jj) * PE_SCALE);
    mpe[c] = (c & 1) ? cosf(ang) : sinf(ang);
  }
  __syncthreads();
  if (tid < 32) {
    int jj = tid;
    float acc = b_p1[jj];
#pragma unroll
    for (int c = 0; c < CC; ++c) acc += mpe[c] * w_p1[c * 32 + jj];
    float a = g_p1[jj] / sqrtf(1.f + EPSBN);
    ws[OFF_M1 + (size_t)(b * KK + k) * 32 + jj] = acc * a + be_p1[jj];
  }
}

// ---------------- K3 fused: P-GEMM (8k x 8q tiles, k-halved m1t) + ctx
// DS/FMA halved vs round-11 (2xb128 m1 + 2xb128 w2 + 1xb32 per 64 FMA).
// 4 nn wave-parallel (nn = tid>>6, wave-uniform xi1 broadcast). Pi kept in
// LDS; k3b phases inlined (xIl/xEl overlay dead m1t). LDS ~27 KB.
__global__ __launch_bounds__(256) void k3_fused(
    const float* __restrict__ w_p2, const float* __restrict__ b_p2,
    const float* __restrict__ g_p2, const float* __restrict__ be_p2,
    const float* __restrict__ w_p3, const float* __restrict__ b_p3,
    float* __restrict__ ws) {
  __shared__ __align__(16) float m1t[32 * 132];   // 16.9 KB, m1^T half [j][kl]
  __shared__ __align__(16) float w2s[1024];       // 4 KB, scaled W2 [j][q]
  __shared__ __align__(16) float Pis[4][256];     // 4 KB
  __shared__ __align__(16) float nekl[256];       // 1 KB
  __shared__ __align__(16) float xi1s[4][32];
  __shared__ __align__(16) float c2f[32];
  __shared__ __align__(16) float w3l[32];
  __shared__ float sI[4], sE[4];
  int tid = threadIdx.x;
  int b = blockIdx.x >> 9;                        // grid = BS*NN/4 = 1024
  int n0 = (blockIdx.x & 511) * 4;
  int nn  = tid >> 6;                             // wave-uniform
  int kgl = (tid >> 2) & 15;
  int qg  = tid & 3;
  int k0l = kgl * 8, q0 = qg * 8;
  // --- prologue ---
  for (int e = tid; e < 1024; e += 256) {
    int q = e & 31;
    w2s[e] = w_p2[e] * (g_p2[q] / sqrtf(1.f + EPSBN));
  }
  if (tid < 32) {
    c2f[tid] = b_p2[tid] * (g_p2[tid] / sqrtf(1.f + EPSBN)) + be_p2[tid];
    w3l[tid] = w_p3[tid];
  }
  if (tid < 128) {
    int n4 = tid >> 5, jx = tid & 31;
    xi1s[n4][jx] = ws[OFF_XI1 + (size_t)(b * NN + n0 + n4) * 32 + jx];
  }
  nekl[tid] = ws[OFF_NEK + b * KK + tid];
  float b3 = b_p3[0];
  __syncthreads();
  float4 cva = *(const float4*)&c2f[q0];
  float4 cvb = *(const float4*)&c2f[q0 + 4];
  float4 w3a = *(const float4*)&w3l[q0];
  float4 w3b = *(const float4*)&w3l[q0 + 4];
#pragma unroll 1
  for (int kh = 0; kh < 2; ++kh) {
    // stage m1^T for this k-half
    for (int e = tid; e < 1024; e += 256) {
      int kl = e >> 3, q = e & 7;
      float4 v = *(const float4*)(ws + OFF_M1 +
                   (size_t)(b * KK + kh * 128 + kl) * 32 + q * 4);
      m1t[(q * 4 + 0) * 132 + kl] = v.x;
      m1t[(q * 4 + 1) * 132 + kl] = v.y;
      m1t[(q * 4 + 2) * 132 + kl] = v.z;
      m1t[(q * 4 + 3) * 132 + kl] = v.w;
    }
    __syncthreads();
    float z[8][8];
#pragma unroll
    for (int i = 0; i < 8; ++i) {
      z[i][0] = cva.x; z[i][1] = cva.y; z[i][2] = cva.z; z[i][3] = cva.w;
      z[i][4] = cvb.x; z[i][5] = cvb.y; z[i][6] = cvb.z; z[i][7] = cvb.w;
    }
#pragma unroll 4
    for (int jj = 0; jj < 32; ++jj) {
      float xv = xi1s[nn][jj];
      const float4* mr = (const float4*)&m1t[jj * 132 + k0l];
      float4 ma = mr[0], mb = mr[1];
      const float4* wr = (const float4*)&w2s[jj * 32 + q0];
      float4 wa = wr[0], wb = wr[1];
      float h0 = fmaxf(0.f, xv + ma.x), h1 = fmaxf(0.f, xv + ma.y);
      float h2 = fmaxf(0.f, xv + ma.z), h3 = fmaxf(0.f, xv + ma.w);
      float h4 = fmaxf(0.f, xv + mb.x), h5 = fmaxf(0.f, xv + mb.y);
      float h6 = fmaxf(0.f, xv + mb.z), h7 = fmaxf(0.f, xv + mb.w);
#define ZROW(i, hh) \
      z[i][0] += hh * wa.x; z[i][1] += hh * wa.y; z[i][2] += hh * wa.z; z[i][3] += hh * wa.w; \
      z[i][4] += hh * wb.x; z[i][5] += hh * wb.y; z[i][6] += hh * wb.z; z[i][7] += hh * wb.w;
      ZROW(0, h0) ZROW(1, h1) ZROW(2, h2) ZROW(3, h3)
      ZROW(4, h4) ZROW(5, h5) ZROW(6, h6) ZROW(7, h7)
#undef ZROW
    }
    // epilogue: w3 partial dot per k, butterfly over the 4 qg lanes
    float s[8];
#pragma unroll
    for (int i = 0; i < 8; ++i)
      s[i] = fmaxf(0.f, z[i][0]) * w3a.x + fmaxf(0.f, z[i][1]) * w3a.y
           + fmaxf(0.f, z[i][2]) * w3a.z + fmaxf(0.f, z[i][3]) * w3a.w
           + fmaxf(0.f, z[i][4]) * w3b.x + fmaxf(0.f, z[i][5]) * w3b.y
           + fmaxf(0.f, z[i][6]) * w3b.z + fmaxf(0.f, z[i][7]) * w3b.w;
#pragma unroll
    for (int i = 0; i < 8; ++i) {
      s[i] += __shfl_xor(s[i], 1, 64);
      s[i] += __shfl_xor(s[i], 2, 64);
    }
    // lane qg owns k = k0l+qg and k0l+4+qg (4-way ternary, rule #20)
    float sv0 = qg < 2 ? (qg == 0 ? s[0] : s[1]) : (qg == 2 ? s[2] : s[3]);
    float sv1 = qg < 2 ? (qg == 0 ? s[4] : s[5]) : (qg == 2 ? s[6] : s[7]);
    int kg0 = kh * 128 + k0l;
    float P0 = 1.f / (1.f + expf(-(sv0 + b3)));
    float P1 = 1.f / (1.f + expf(-(sv1 + b3)));
    Pis[nn][kg0 + qg]     = P0 * nekl[kg0 + qg];
    Pis[nn][kg0 + 4 + qg] = P1 * nekl[kg0 + 4 + qg];
    __syncthreads();                              // m1t reuse / Pis publish
  }
  // ---- ctx phases (xIl/xEl overlay dead m1t) ----
  float* xIl = m1t;                               // 272 floats
  float* xEl = m1t + 272;
  // sums over k (Pe = nek - Pi)
  if (tid < 128) {
    int n4 = tid >> 5, jx = tid & 31;
    float s1 = 0.f, s2 = 0.f;
#pragma unroll
    for (int t = 0; t < 8; ++t) {
      float pi = Pis[n4][jx + 32 * t];
      s1 += pi;
      s2 += nekl[jx + 32 * t] - pi;
    }
    for (int off = 16; off > 0; off >>= 1) {
      s1 += __shfl_down(s1, off, 32);
      s2 += __shfl_down(s2, off, 32);
    }
    if (jx == 0) { sI[n4] = s1; sE[n4] = s2; }
  }
  __syncthreads();
  // x_intra/x_inter: thread = (n, c)
  {
    int c = tid & 63, n = tid >> 6;
    const float4* PI4 = (const float4*)Pis[n];
    const float4* NE4 = (const float4*)nekl;
    const float* tfg = ws + OFF_TF + (size_t)b * KK * CC + c;
    float aI = 0.f, aE = 0.f;
#pragma unroll 4
    for (int kq = 0; kq < 64; ++kq) {
      float4 piv = PI4[kq], nev = NE4[kq];
      float t0 = tfg[(4 * kq + 0) * 64];
      float t1 = tfg[(4 * kq + 1) * 64];
      float t2 = tfg[(4 * kq + 2) * 64];
      float t3 = tfg[(4 * kq + 3) * 64];
      aI += piv.x * t0 + piv.y * t1 + piv.z * t2 + piv.w * t3;
      aE += (nev.x - piv.x) * t0 + (nev.y - piv.y) * t1
          + (nev.z - piv.z) * t2 + (nev.w - piv.w) * t3;
    }
    xIl[n * 68 + c] = aI / sI[n];
    xEl[n * 68 + c] = aE / sE[n];
  }
  __syncthreads();
  // delta = xI @ WF[64:128] + xE @ WF[128:192]
  {
    int co = tid & 63, n4 = tid >> 6;
    const float4* xI4 = (const float4*)&xIl[n4 * 68];
    const float4* xE4 = (const float4*)&xEl[n4 * 68];
    const float* wI = ws + OFF_WF + 64 * CC + co;
    const float* wE = ws + OFF_WF + 128 * CC + co;
    float dsum = 0.f;
#pragma unroll 4
    for (int cq = 0; cq < 16; ++cq) {
      float4 xi4 = xI4[cq], xe4 = xE4[cq];
      dsum += xi4.x * wI[(4 * cq + 0) * 64] + xi4.y * wI[(4 * cq + 1) * 64]
            + xi4.z * wI[(4 * cq + 2) * 64] + xi4.w * wI[(4 * cq + 3) * 64];
      dsum += xe4.x * wE[(4 * cq + 0) * 64] + xe4.y * wE[(4 * cq + 1) * 64]
            + xe4.z * wE[(4 * cq + 2) * 64] + xe4.w * wE[(4 * cq + 3) * 64];
    }
    ws[OFF_DELTA + (size_t)(b * NN + n0 + n4) * CC + co] = dsum;
  }
}

// ---------------- K4: base resize + masked delta add, coalesced single store
__global__ __launch_bounds__(256) void k4_out(
    const float* __restrict__ input, float* __restrict__ out,
    const float* __restrict__ ws) {
  __shared__ __align__(16) float wfa[64 * 64];
  __shared__ float bfl[64];
  int tid = threadIdx.x;
  const float* wf = ws + OFF_WF;
  for (int e = tid; e < 4096; e += 256) {
    int c = e >> 6, co = e & 63;
    wfa[e] = wf[c * 64 + co] + wf[(192 + c) * 64 + co];
  }
  if (tid < 64) bfl[tid] = ws[OFF_BF + tid];
  __syncthreads();
  int q = tid >> 6, lane = tid & 63;
  int pg = blockIdx.x * 64 + lane;             // grid = BS*FLAT/64 = 512
  int b = pg >> 14, pos = pg & (FLAT - 1);
  const int* inv = (const int*)(ws + OFF_INV);
  float acc[16];
#pragma unroll
  for (int u = 0; u < 16; ++u) acc[u] = bfl[q * 16 + u];
#pragma unroll 4
  for (int c = 0; c < 64; ++c) {
    float xv = input[((size_t)(b * CC + c)) * FLAT + pos];
    const float4* wr = (const float4*)&wfa[c * 64 + q * 16];
#pragma unroll
    for (int u4 = 0; u4 < 4; ++u4) {
      float4 w = wr[u4];
      acc[u4 * 4 + 0] += xv * w.x; acc[u4 * 4 + 1] += xv * w.y;
      acc[u4 * 4 + 2] += xv * w.z; acc[u4 * 4 + 3] += xv * w.w;
    }
  }
  int n = inv[pg];
  if (n >= 0) {
    const float4* dr = (const float4*)(ws + OFF_DELTA + (size_t)(b * NN + n) * CC + q * 16);
#pragma unroll
    for (int u4 = 0; u4 < 4; ++u4) {
      float4 dv = dr[u4];
      acc[u4 * 4 + 0] += dv.x; acc[u4 * 4 + 1] += dv.y;
      acc[u4 * 4 + 2] += dv.z; acc[u4 * 4 + 3] += dv.w;
    }
  }
#pragma unroll
  for (int u = 0; u < 16; ++u)
    out[((size_t)(b * CC + q * 16 + u)) * FLAT + pos] = acc[u];
}

// ---------------- launch ----------------
extern "C" void kernel_launch(void* const* d_in, const int* in_sizes, int n_in,
                              void* d_out, int out_size, void* d_ws, size_t ws_size,
                              hipStream_t stream) {
  const float* input = (const float*)d_in[0];
  const int*   midx  = (const int*)  d_in[1];
  const float* w_ne1 = (const float*)d_in[2];
  const float* b_ne1 = (const float*)d_in[3];
  const float* g_ne  = (const float*)d_in[4];
  const float* be_ne = (const float*)d_in[5];
  const float* w_ne2 = (const float*)d_in[6];
  const float* b_ne2 = (const float*)d_in[7];
  const float* w_p1  = (const float*)d_in[8];
  const float* b_p1  = (const float*)d_in[9];
  const float* g_p1  = (const float*)d_in[10];
  const float* be_p1 = (const float*)d_in[11];
  const float* w_p2  = (const float*)d_in[12];
  const float* b_p2  = (const float*)d_in[13];
  const float* g_p2  = (const float*)d_in[14];
  const float* be_p2 = (const float*)d_in[15];
  const float* w_p3  = (const float*)d_in[16];
  const float* b_p3  = (const float*)d_in[17];
  const float* w_r1  = (const float*)d_in[18];
  const float* b_r1  = (const float*)d_in[19];
  const float* w_r2  = (const float*)d_in[20];
  const float* b_r2  = (const float*)d_in[21];
  float* out = (float*)d_out;
  float* ws  = (float*)d_ws;

  k0_fold<<<dim3(256), dim3(64), 0, stream>>>(w_r1, b_r1, w_r2, b_r2, ws);
  k1_xi<<<dim3(BS * NN / 8), dim3(256), 0, stream>>>(
      input, midx, w_ne1, b_ne1, g_ne, be_ne, w_ne2, b_ne2, w_p1, g_p1, ws);
  k2_sample<<<dim3(BS * KK), dim3(256), 0, stream>>>(
      midx, w_p1, b_p1, g_p1, be_p1, ws);
  k3_fused<<<dim3(BS * NN / 4), dim3(256), 0, stream>>>(
      w_p2, b_p2, g_p2, be_p2, w_p3, b_p3, ws);
  k4_out<<<dim3(BS * FLAT / 64), dim3(256), 0, stream>>>(input, out, ws);
}